// Round 21
// baseline (123.651 us; speedup 1.0000x reference)
//
#include <hip/hip_runtime.h>
#include <hip/hip_bf16.h>

// GAT layer, round 21: r20 (109.7us) with k_bucket regranularized to
// BSZ=32 / 3125 blocks (12.2 blocks/CU -> occupancy-fed gather; tail halved).
// k_bin keeps LDS at 80KB by aliasing cursor into the prefix array.
// XCD swizzle keeps the finer-run writes same-XCD (r16 lesson).
// N=100000, F=128, H=64, E=1.6M.

#define LEAKY 0.05f
#define BSH   5                  // nodes per bucket = 32
#define BSZ   32
#define EPB   4096               // edges per segment
#define MAXIT 3
#define CAPB  (MAXIT * 256)      // 768 cap (mean 512, +11 sigma)
#define NBMAX 4096               // NB = 3125
#define NXCD  8

using bf16x8 = __attribute__((ext_vector_type(8))) __bf16;
using f32x4  = __attribute__((ext_vector_type(4))) float;

__device__ __forceinline__ int wave_scan_incl(int v, int lane) {
#pragma unroll
    for (int off = 1; off < 64; off <<= 1) {
        int u = __shfl_up(v, off);
        if (lane >= off) v += u;
    }
    return v;
}
__device__ __forceinline__ unsigned short f2bf(float f) {   // RNE bf16
    unsigned u = __float_as_uint(f);
    return (unsigned short)((u + 0x7FFF + ((u >> 16) & 1)) >> 16);
}
__device__ __forceinline__ float bf2f(unsigned short u) {
    return __uint_as_float((unsigned)u << 16);
}
__device__ __forceinline__ bf16x8 pack8(const float* p) {
    float4 lo = *(const float4*)p;
    float4 hi = *(const float4*)(p + 4);
    bf16x8 v;
    v[0] = (__bf16)lo.x; v[1] = (__bf16)lo.y; v[2] = (__bf16)lo.z; v[3] = (__bf16)lo.w;
    v[4] = (__bf16)hi.x; v[5] = (__bf16)hi.y; v[6] = (__bf16)hi.z; v[7] = (__bf16)hi.w;
    return v;
}
__device__ __forceinline__ float leaky_exp(float t) {
    t = (t >= 0.f) ? t : LEAKY * t;
    return __expf(t);
}
// bijective XCD swizzle (m204): consecutive logical ids on same XCD
__device__ __forceinline__ int xcd_swz(int i, int n) {
    int q = n / NXCD, r = n % NXCD;
    int xcd = i % NXCD, j = i / NXCD;
    return (xcd < r) ? xcd * (q + 1) + j : r * (q + 1) + (xcd - r) * q + j;
}

// ---------------------------------------------------------------------------
// K1 (fused): blocks [0,lgrid) -> MFMA linear (4 tiles/wave); rest -> histogram.
__global__ __launch_bounds__(256) void k_linear_hist(
    const float* __restrict__ x, const float* __restrict__ fc_w,
    const float* __restrict__ a_w, const float* __restrict__ a_b,
    unsigned short* __restrict__ h0b, float* __restrict__ s_src,
    float* __restrict__ s_dst,
    const int* __restrict__ src, int* __restrict__ Hist,
    int N, int E, int NB, int lgrid)
{
    __shared__ int hist[NBMAX];

    if (blockIdx.x >= lgrid) {
        const int seg = blockIdx.x - lgrid;
        for (int b = threadIdx.x; b < NB; b += 256) hist[b] = 0;
        __syncthreads();
        const int e0 = seg * EPB;
#pragma unroll
        for (int k = 0; k < EPB / 1024; ++k) {
            int e = e0 + k * 1024 + threadIdx.x * 4;
            if (e + 3 < E) {
                int4 s4 = *(const int4*)&src[e];
                atomicAdd(&hist[s4.x >> BSH], 1);
                atomicAdd(&hist[s4.y >> BSH], 1);
                atomicAdd(&hist[s4.z >> BSH], 1);
                atomicAdd(&hist[s4.w >> BSH], 1);
            } else {
                for (int q = e; q < E; ++q) atomicAdd(&hist[src[q] >> BSH], 1);
            }
        }
        __syncthreads();
        for (int b = threadIdx.x; b < NB; b += 256)
            Hist[seg * NB + b] = hist[b];
        return;
    }

    // ---- MFMA linear: one wave = 4 tiles = 64 nodes (B frags reused) ----
    const int wave = threadIdx.x >> 6, lane = threadIdx.x & 63;
    const int row = lane & 15, grp = lane >> 4;

    bf16x8 bf[4][4];
#pragma unroll
    for (int nt = 0; nt < 4; ++nt) {
        const float* wrow = fc_w + (size_t)(nt * 16 + row) * 128;
#pragma unroll
        for (int kb = 0; kb < 4; ++kb)
            bf[nt][kb] = pack8(wrow + kb * 32 + grp * 8);
    }
    float aw0[4], aw1[4];
#pragma unroll
    for (int nt = 0; nt < 4; ++nt) {
        aw0[nt] = a_w[nt * 16 + row];
        aw1[nt] = a_w[64 + nt * 16 + row];
    }
    const float ab = a_b[0];

    const int nbase = blockIdx.x * 256 + wave * 64;
    if (nbase >= N) return;

#pragma unroll
    for (int tt = 0; tt < 4; ++tt) {
        const int tbase = nbase + tt * 16;
        if (tbase >= N) break;
        const int node = min(tbase + row, N - 1);

        bf16x8 af[4];
#pragma unroll
        for (int kb = 0; kb < 4; ++kb)
            af[kb] = pack8(x + (size_t)node * 128 + kb * 32 + grp * 8);

        f32x4 acc[4];
#pragma unroll
        for (int nt = 0; nt < 4; ++nt) acc[nt] = (f32x4){0.f, 0.f, 0.f, 0.f};

#pragma unroll
        for (int nt = 0; nt < 4; ++nt)
#pragma unroll
            for (int kb = 0; kb < 4; ++kb)
                acc[nt] = __builtin_amdgcn_mfma_f32_16x16x32_bf16(
                    af[kb], bf[nt][kb], acc[nt], 0, 0, 0);

#pragma unroll
        for (int nt = 0; nt < 4; ++nt)
#pragma unroll
            for (int r = 0; r < 4; ++r) {
                int nrow = tbase + grp * 4 + r;
                if (nrow < N)
                    h0b[(size_t)nrow * 64 + nt * 16 + row] = f2bf(acc[nt][r]);
            }

#pragma unroll
        for (int r = 0; r < 4; ++r) {
            float p0 = 0.f, p1 = 0.f;
#pragma unroll
            for (int nt = 0; nt < 4; ++nt) {
                p0 += acc[nt][r] * aw0[nt];
                p1 += acc[nt][r] * aw1[nt];
            }
#pragma unroll
            for (int off = 1; off < 16; off <<= 1) {
                p0 += __shfl_xor(p0, off);
                p1 += __shfl_xor(p1, off);
            }
            int nrow = tbase + grp * 4 + r;
            if (row == 0 && nrow < N) { s_src[nrow] = p0 + ab; s_dst[nrow] = p1; }
        }
    }
}

// ---------------------------------------------------------------------------
// K2: column scan of Hist -> Base[seg][b] + coltot[b]   (NEB <= 512)
__global__ __launch_bounds__(512) void k_colscan(
    const int* __restrict__ Hist, int* __restrict__ Base,
    int* __restrict__ coltot, int NEB, int NB)
{
    __shared__ int wsum[8];
    const int b = blockIdx.x;
    const int t = threadIdx.x, wv = t >> 6, lane = t & 63;
    int v = (t < NEB) ? Hist[t * NB + b] : 0;
    int incl = wave_scan_incl(v, lane);
    if (lane == 63) wsum[wv] = incl;
    __syncthreads();
    int woff = 0;
    for (int w = 0; w < wv; ++w) woff += wsum[w];
    if (t < NEB) Base[t * NB + b] = woff + incl - v;
    if (t == NEB - 1) coltot[b] = woff + incl;
}

// ---------------------------------------------------------------------------
// K3: per-segment LDS sort + ORDERED global placement; streams h (bf16).
// Each block scans coltot -> local boff (ordered regions); block 0 publishes
// boff for k_bucket. blockIdx -> seg via bijective XCD swizzle.
// Cursor aliases into hist (it holds the local exclusive prefix already).
__global__ __launch_bounds__(512) void k_bin(
    const int* __restrict__ src, const int* __restrict__ dst,
    const float* __restrict__ adj,
    const float* __restrict__ s_src, const float* __restrict__ s_dst,
    const int* __restrict__ coltot, const int* __restrict__ Base,
    int* __restrict__ boff,
    int2* __restrict__ binned, unsigned short* __restrict__ h_bf,
    int E, int NB, int NEB)
{
    __shared__ int  hist[NBMAX];     // counts -> local prefix -> cursor
    __shared__ int  gbase[NBMAX];    // lboff, then global base per bucket
    __shared__ int  wpart[8];
    __shared__ int2 stage[EPB];      // 32 KB
    __shared__ int  gaddr[EPB];      // 16 KB

    const int t = threadIdx.x;
    const int seg = xcd_swz(blockIdx.x, NEB);
    const int e0 = seg * EPB;
    const int segcnt = min(EPB, E - e0);
    const int lane = t & 63, wv = t >> 6;
    const int C = (NB + 511) / 512;  // 7 at NB=3125

    // ---- phase 0: scan coltot -> lboff (into gbase); block 0 -> boff ----
    {
        const int lo = t * C, hiB = min(NB, lo + C);
        int cv[8];
        int ssum = 0;
        for (int b = lo; b < hiB; ++b) { cv[b - lo] = coltot[b]; ssum += cv[b - lo]; }
        int incl = wave_scan_incl(ssum, lane);
        if (lane == 63) wpart[wv] = incl;
        __syncthreads();
        int woff = 0;
        for (int w2 = 0; w2 < wv; ++w2) woff += wpart[w2];
        int run = woff + incl - ssum;
        for (int b = lo; b < hiB; ++b) { gbase[b] = run; run += cv[b - lo]; }
        __syncthreads();
        if (blockIdx.x == 0)
            for (int b = t; b < NB; b += 512) boff[b] = gbase[b];
    }

    for (int b = t; b < NB; b += 512) hist[b] = 0;
    __syncthreads();

    // load 8 edges/thread, build records, LDS histogram, persist h_bf
    int rw0[8], rw1[8], bkt[8];
#pragma unroll
    for (int k = 0; k < 2; ++k) {
        int e = e0 + k * 2048 + t * 4;
        if (e + 3 < E) {
            int4   s4 = *(const int4*)&src[e];
            int4   d4 = *(const int4*)&dst[e];
            float4 a4 = *(const float4*)&adj[e];
            ushort4 hb;
#pragma unroll
            for (int q = 0; q < 4; ++q) {
                const int i = k * 4 + q;
                int s = (&s4.x)[q], d = (&d4.x)[q];
                float h = leaky_exp(s_src[s] + s_dst[d]);
                float v = h * (&a4.x)[q];
                unsigned short hb16 = f2bf(h);
                (&hb.x)[q] = hb16;
                rw0[i] = d | ((s & (BSZ - 1)) << 24);
                rw1[i] = (int)(((unsigned)hb16 << 16) | f2bf(v));
                bkt[i] = s >> BSH;
                atomicAdd(&hist[bkt[i]], 1);
            }
            *(ushort4*)&h_bf[e] = hb;
        } else {
#pragma unroll
            for (int q = 0; q < 4; ++q) {
                const int i = k * 4 + q;
                int ee = e + q;
                if (ee < E) {
                    int s = src[ee], d = dst[ee];
                    float h = leaky_exp(s_src[s] + s_dst[d]);
                    float v = h * adj[ee];
                    unsigned short hb16 = f2bf(h);
                    h_bf[ee] = hb16;
                    rw0[i] = d | ((s & (BSZ - 1)) << 24);
                    rw1[i] = (int)(((unsigned)hb16 << 16) | f2bf(v));
                    bkt[i] = s >> BSH;
                    atomicAdd(&hist[bkt[i]], 1);
                } else bkt[i] = -1;
            }
        }
    }
    __syncthreads();

    // block exclusive scan of hist[0..NB) in place (512 threads)
    {
        const int lo = t * C, hiB = min(NB, lo + C);
        int ssum = 0;
        for (int b = lo; b < hiB; ++b) ssum += hist[b];
        int incl = wave_scan_incl(ssum, lane);
        if (lane == 63) wpart[wv] = incl;
        __syncthreads();
        int woff = 0;
        for (int w2 = 0; w2 < wv; ++w2) woff += wpart[w2];
        int run = woff + incl - ssum;
        for (int b = lo; b < hiB; ++b) { int v = hist[b]; hist[b] = run; run += v; }
        __syncthreads();
    }

    // global base per bucket (hist keeps lpref and becomes the cursor)
    for (int b = t; b < NB; b += 512)
        gbase[b] = gbase[b] + Base[seg * NB + b] - hist[b];
    __syncthreads();

    // place records into sorted LDS slots + record their global address
#pragma unroll
    for (int i = 0; i < 8; ++i) {
        if (bkt[i] >= 0) {
            int pos = atomicAdd(&hist[bkt[i]], 1);
            stage[pos] = make_int2(rw0[i], rw1[i]);
            gaddr[pos] = gbase[bkt[i]] + pos;
        }
    }
    __syncthreads();

    // ordered write-out: consecutive j -> monotone ascending gaddr
    for (int j = t; j < segcnt; j += 512)
        binned[gaddr[j]] = stage[j];
}

// ---------------------------------------------------------------------------
// K4: per-bucket contiguous records -> LDS CSR + dual-node quad-gather.
// BSZ=32, 256 thr / 4 waves; wave pairs (n, n+4), stride 8.
__global__ __launch_bounds__(256) void k_bucket(
    const int2* __restrict__ binned, const int* __restrict__ boff,
    const int* __restrict__ coltot,
    const unsigned short* __restrict__ h0b, float* __restrict__ out,
    float* __restrict__ inv_hsum_g, int N)
{
    __shared__ int   deg_cur[BSZ];
    __shared__ int   pref[BSZ + 1];
    __shared__ int2  rec[CAPB];       // {dst, h_bf<<16 | v_bf}

    const int b   = blockIdx.x;
    const int lo  = boff[b];
    const int cnt = coltot[b];
    const int hi  = lo + cnt;
    const int n0 = b << BSH;
    const int nn = min(BSZ, N - n0);
    const int t = threadIdx.x, wv = t >> 6, lane = t & 63;

    if (t < BSZ) deg_cur[t] = 0;
    __syncthreads();

    if (cnt <= CAPB) {
        int2 r[MAXIT];
#pragma unroll
        for (int it = 0; it < MAXIT; ++it) {
            int j = lo + it * 256 + t;
            if (j < hi) r[it] = binned[j];
        }
#pragma unroll
        for (int it = 0; it < MAXIT; ++it)
            if (lo + it * 256 + t < hi)
                atomicAdd(&deg_cur[(unsigned)r[it].x >> 24], 1);
        __syncthreads();

        // single-wave scan over BSZ degrees
        if (wv == 0) {
            int v = (lane < BSZ) ? deg_cur[lane] : 0;
            int incl = wave_scan_incl(v, lane);
            if (lane < BSZ) {
                pref[lane + 1] = incl;
                deg_cur[lane] = incl - v;    // cursor = exclusive prefix
            }
            if (lane == 0) pref[0] = 0;
        }
        __syncthreads();

#pragma unroll
        for (int it = 0; it < MAXIT; ++it) {
            if (lo + it * 256 + t < hi) {
                int2 rr = r[it];
                int node = (unsigned)rr.x >> 24;
                int pos = atomicAdd(&deg_cur[node], 1);
                rec[pos] = make_int2(rr.x & 0xFFFFFF, rr.y);
            }
        }
        __syncthreads();

        // dual-node quad-gather: wave handles (nA, nA+4); h-sum in-reduce
        const int eslot = lane >> 4, fq = lane & 15;
        for (int nA = wv; nA < nn; nA += 8) {
            const int nB = nA + 4;
            const bool hasB = (nB < nn);
            const int sA = pref[nA], eA2 = pref[nA + 1];
            const int sB = hasB ? pref[nB] : 0, eB2 = hasB ? pref[nB + 1] : 0;

            float aA[4] = {0.f, 0.f, 0.f, 0.f}, bA[4] = {0.f, 0.f, 0.f, 0.f};
            float aB[4] = {0.f, 0.f, 0.f, 0.f}, bB[4] = {0.f, 0.f, 0.f, 0.f};
            float hA = 0.f, hB = 0.f;

            const int roundsA = (eA2 - sA + 7) >> 3;
            const int roundsB = (eB2 - sB + 7) >> 3;
            const int rounds  = max(roundsA, roundsB);

            for (int rr2 = 0; rr2 < rounds; ++rr2) {
                const int bA2 = sA + rr2 * 8;
                const int bB2 = sB + rr2 * 8;
                int idxA0 = bA2 + eslot,     idxA1 = bA2 + 4 + eslot;
                int idxB0 = bB2 + eslot,     idxB1 = bB2 + 4 + eslot;
                bool vA0 = idxA0 < eA2, vA1 = idxA1 < eA2;
                bool vB0 = hasB && idxB0 < eB2, vB1 = hasB && idxB1 < eB2;
                int2 rA0 = rec[vA0 ? idxA0 : 0];
                int2 rA1 = rec[vA1 ? idxA1 : 0];
                int2 rB0 = rec[vB0 ? idxB0 : 0];
                int2 rB1 = rec[vB1 ? idxB1 : 0];
                float valA0 = vA0 ? __uint_as_float((unsigned)rA0.y << 16) : 0.f;
                float valA1 = vA1 ? __uint_as_float((unsigned)rA1.y << 16) : 0.f;
                float valB0 = vB0 ? __uint_as_float((unsigned)rB0.y << 16) : 0.f;
                float valB1 = vB1 ? __uint_as_float((unsigned)rB1.y << 16) : 0.f;
                hA += (vA0 ? __uint_as_float((unsigned)rA0.y & 0xFFFF0000u) : 0.f)
                    + (vA1 ? __uint_as_float((unsigned)rA1.y & 0xFFFF0000u) : 0.f);
                hB += (vB0 ? __uint_as_float((unsigned)rB0.y & 0xFFFF0000u) : 0.f)
                    + (vB1 ? __uint_as_float((unsigned)rB1.y & 0xFFFF0000u) : 0.f);
                uint2 uA0 = *(const uint2*)(h0b + (size_t)rA0.x * 64 + fq * 4);
                uint2 uA1 = *(const uint2*)(h0b + (size_t)rA1.x * 64 + fq * 4);
                uint2 uB0 = *(const uint2*)(h0b + (size_t)rB0.x * 64 + fq * 4);
                uint2 uB1 = *(const uint2*)(h0b + (size_t)rB1.x * 64 + fq * 4);
                aA[0] += valA0 * __uint_as_float(uA0.x << 16);
                aA[1] += valA0 * __uint_as_float(uA0.x & 0xFFFF0000u);
                aA[2] += valA0 * __uint_as_float(uA0.y << 16);
                aA[3] += valA0 * __uint_as_float(uA0.y & 0xFFFF0000u);
                bA[0] += valA1 * __uint_as_float(uA1.x << 16);
                bA[1] += valA1 * __uint_as_float(uA1.x & 0xFFFF0000u);
                bA[2] += valA1 * __uint_as_float(uA1.y << 16);
                bA[3] += valA1 * __uint_as_float(uA1.y & 0xFFFF0000u);
                aB[0] += valB0 * __uint_as_float(uB0.x << 16);
                aB[1] += valB0 * __uint_as_float(uB0.x & 0xFFFF0000u);
                aB[2] += valB0 * __uint_as_float(uB0.y << 16);
                aB[3] += valB0 * __uint_as_float(uB0.y & 0xFFFF0000u);
                bB[0] += valB1 * __uint_as_float(uB1.x << 16);
                bB[1] += valB1 * __uint_as_float(uB1.x & 0xFFFF0000u);
                bB[2] += valB1 * __uint_as_float(uB1.y << 16);
                bB[3] += valB1 * __uint_as_float(uB1.y & 0xFFFF0000u);
            }

#pragma unroll
            for (int k = 0; k < 4; ++k) {
                float vv = aA[k] + bA[k];
                vv += __shfl_xor(vv, 16);
                vv += __shfl_xor(vv, 32);
                aA[k] = vv;
                float ww = aB[k] + bB[k];
                ww += __shfl_xor(ww, 16);
                ww += __shfl_xor(ww, 32);
                aB[k] = ww;
            }
            hA += __shfl_xor(hA, 16);
            hA += __shfl_xor(hA, 32);
            hB += __shfl_xor(hB, 16);
            hB += __shfl_xor(hB, 32);

            const float invA = (eA2 > sA) ? 1.0f / hA : 0.f;
            const float invB = (hasB && eB2 > sB) ? 1.0f / hB : 0.f;
            if (lane < 16) {
                float4 o;
                o.x = aA[0] * invA; o.y = aA[1] * invA;
                o.z = aA[2] * invA; o.w = aA[3] * invA;
                *(float4*)&out[(size_t)(n0 + nA) * 64 + fq * 4] = o;
            } else if (hasB && lane < 32) {
                float4 o;
                o.x = aB[0] * invB; o.y = aB[1] * invB;
                o.z = aB[2] * invB; o.w = aB[3] * invB;
                *(float4*)&out[(size_t)(n0 + nB) * 64 + fq * 4] = o;
            }
            if (lane == 0) inv_hsum_g[n0 + nA] = invA;
            if (hasB && lane == 16) inv_hsum_g[n0 + nB] = invB;
        }
    } else {
        // correctness-only fallback (cnt > CAPB is ~11 sigma; never expected)
        for (int n = wv; n < nn; n += 4) {
            float acc = 0.f, hs = 0.f;
            for (int j = lo; j < hi; ++j) {
                int2 rr = binned[j];
                if (((unsigned)rr.x >> 24) == (unsigned)n) {
                    hs  += __uint_as_float((unsigned)rr.y & 0xFFFF0000u);
                    acc += __uint_as_float((unsigned)rr.y << 16) *
                           bf2f(h0b[(size_t)(rr.x & 0xFFFFFF) * 64 + lane]);
                }
            }
            float inv = (hs > 0.f) ? 1.0f / hs : 0.f;
            out[(size_t)(n0 + n) * 64 + lane] = acc * inv;
            if (lane == 0) inv_hsum_g[n0 + n] = inv;
        }
    }
}

// ---------------------------------------------------------------------------
// K5: alpha[e] = h_bf[e] * inv_hsum[src[e]]  (pure stream, x4)
__global__ __launch_bounds__(256) void k_alpha(
    const int* __restrict__ src, const unsigned short* __restrict__ h_bf,
    const float* __restrict__ inv_hsum_g, float* __restrict__ alpha, int E)
{
    int i = blockIdx.x * 256 + threadIdx.x;
    int e = i * 4;
    if (e + 3 < E) {
        ushort4 hb = *(const ushort4*)&h_bf[e];
        int4 s4 = *(const int4*)&src[e];
        float4 a;
        a.x = bf2f(hb.x) * inv_hsum_g[s4.x];
        a.y = bf2f(hb.y) * inv_hsum_g[s4.y];
        a.z = bf2f(hb.z) * inv_hsum_g[s4.z];
        a.w = bf2f(hb.w) * inv_hsum_g[s4.w];
        *(float4*)&alpha[e] = a;
    } else {
        for (; e < E; ++e)
            alpha[e] = bf2f(h_bf[e]) * inv_hsum_g[src[e]];
    }
}

// ---------------------------------------------------------------------------
extern "C" void kernel_launch(void* const* d_in, const int* in_sizes, int n_in,
                              void* d_out, int out_size, void* d_ws, size_t ws_size,
                              hipStream_t stream)
{
    const float* x    = (const float*)d_in[0];
    const int*   ei   = (const int*)d_in[1];
    const float* adj  = (const float*)d_in[2];
    const float* fc_w = (const float*)d_in[3];
    const float* a_w  = (const float*)d_in[4];
    const float* a_b  = (const float*)d_in[5];

    const int N = in_sizes[0] / 128;          // 100000
    const int E = in_sizes[2];                // 1600000
    const int* src = ei;
    const int* dst = ei + E;

    const int NB  = (N + BSZ - 1) >> BSH;     // 3125 buckets
    const int NEB = (E + EPB - 1) / EPB;      // 391 segments

    float* out   = (float*)d_out;
    float* alpha = out + (size_t)N * 64;

    char* w = (char*)d_ws;
    auto carve = [&](size_t bytes) {
        char* p = w;
        w += (bytes + 255) & ~(size_t)255;
        return p;
    };
    unsigned short* h0b  = (unsigned short*)carve((size_t)N * 64 * 2);
    float* s_src   = (float*)carve((size_t)N * 4);
    float* s_dst   = (float*)carve((size_t)N * 4);
    float* inv_hs  = (float*)carve((size_t)N * 4);
    unsigned short* h_bf = (unsigned short*)carve((size_t)E * 2);
    int*   Hist    = (int*)  carve((size_t)NEB * NB * 4);
    int*   Base    = (int*)  carve((size_t)NEB * NB * 4);
    int*   coltot  = (int*)  carve((size_t)NB * 4);
    int*   boff    = (int*)  carve((size_t)NB * 4);
    int2*  binned  = (int2*) carve((size_t)E * 8);

    const int lgrid = (N + 255) / 256;         // 391 linear blocks (4 tiles/wave)

    k_linear_hist<<<lgrid + NEB, 256, 0, stream>>>(
        x, fc_w, a_w, a_b, h0b, s_src, s_dst, src, Hist, N, E, NB, lgrid);
    k_colscan<<<NB, 512, 0, stream>>>(Hist, Base, coltot, NEB, NB);
    k_bin<<<NEB, 512, 0, stream>>>(src, dst, adj, s_src, s_dst, coltot, Base,
                                   boff, binned, h_bf, E, NB, NEB);
    k_bucket<<<NB, 256, 0, stream>>>(binned, boff, coltot, h0b, out, inv_hs, N);
    k_alpha<<<(E / 4 + 255) / 256, 256, 0, stream>>>(src, h_bf, inv_hs, alpha, E);
}

// Round 22
// 113.154 us; speedup vs baseline: 1.0928x; 1.0928x over previous
//
#include <hip/hip_runtime.h>
#include <hip/hip_bf16.h>

// GAT layer, round 22: r20 (109.7us best) with k_bin destaged:
// records written DIRECTLY from registers to their global CSR position
// (stage/gaddr LDS arrays deleted -> 80KB -> ~13KB, 4 blocks/CU).
// Post-r16 XCD swizzle makes write order within a block irrelevant
// (same-XCD L2 merges partial lines). BSZ=64 / NB=1563 equilibrium kept.
// N=100000, F=128, H=64, E=1.6M.

#define LEAKY 0.05f
#define BSH   6                  // nodes per bucket = 64
#define BSZ   64
#define EPB   4096               // edges per segment
#define MAXIT 6
#define CAPB  (MAXIT * 256)      // 1536 cap (mean 1023, +16 sigma)
#define NBMAX 2048               // NB = 1563
#define NXCD  8

using bf16x8 = __attribute__((ext_vector_type(8))) __bf16;
using f32x4  = __attribute__((ext_vector_type(4))) float;

__device__ __forceinline__ int wave_scan_incl(int v, int lane) {
#pragma unroll
    for (int off = 1; off < 64; off <<= 1) {
        int u = __shfl_up(v, off);
        if (lane >= off) v += u;
    }
    return v;
}
__device__ __forceinline__ unsigned short f2bf(float f) {   // RNE bf16
    unsigned u = __float_as_uint(f);
    return (unsigned short)((u + 0x7FFF + ((u >> 16) & 1)) >> 16);
}
__device__ __forceinline__ float bf2f(unsigned short u) {
    return __uint_as_float((unsigned)u << 16);
}
__device__ __forceinline__ bf16x8 pack8(const float* p) {
    float4 lo = *(const float4*)p;
    float4 hi = *(const float4*)(p + 4);
    bf16x8 v;
    v[0] = (__bf16)lo.x; v[1] = (__bf16)lo.y; v[2] = (__bf16)lo.z; v[3] = (__bf16)lo.w;
    v[4] = (__bf16)hi.x; v[5] = (__bf16)hi.y; v[6] = (__bf16)hi.z; v[7] = (__bf16)hi.w;
    return v;
}
__device__ __forceinline__ float leaky_exp(float t) {
    t = (t >= 0.f) ? t : LEAKY * t;
    return __expf(t);
}
// bijective XCD swizzle (m204): consecutive logical ids on same XCD
__device__ __forceinline__ int xcd_swz(int i, int n) {
    int q = n / NXCD, r = n % NXCD;
    int xcd = i % NXCD, j = i / NXCD;
    return (xcd < r) ? xcd * (q + 1) + j : r * (q + 1) + (xcd - r) * q + j;
}

// ---------------------------------------------------------------------------
// K1 (fused): blocks [0,lgrid) -> MFMA linear (4 tiles/wave); rest -> histogram.
__global__ __launch_bounds__(256) void k_linear_hist(
    const float* __restrict__ x, const float* __restrict__ fc_w,
    const float* __restrict__ a_w, const float* __restrict__ a_b,
    unsigned short* __restrict__ h0b, float* __restrict__ s_src,
    float* __restrict__ s_dst,
    const int* __restrict__ src, int* __restrict__ Hist,
    int N, int E, int NB, int lgrid)
{
    __shared__ int hist[NBMAX];

    if (blockIdx.x >= lgrid) {
        const int seg = blockIdx.x - lgrid;
        for (int b = threadIdx.x; b < NB; b += 256) hist[b] = 0;
        __syncthreads();
        const int e0 = seg * EPB;
#pragma unroll
        for (int k = 0; k < EPB / 1024; ++k) {
            int e = e0 + k * 1024 + threadIdx.x * 4;
            if (e + 3 < E) {
                int4 s4 = *(const int4*)&src[e];
                atomicAdd(&hist[s4.x >> BSH], 1);
                atomicAdd(&hist[s4.y >> BSH], 1);
                atomicAdd(&hist[s4.z >> BSH], 1);
                atomicAdd(&hist[s4.w >> BSH], 1);
            } else {
                for (int q = e; q < E; ++q) atomicAdd(&hist[src[q] >> BSH], 1);
            }
        }
        __syncthreads();
        for (int b = threadIdx.x; b < NB; b += 256)
            Hist[seg * NB + b] = hist[b];
        return;
    }

    // ---- MFMA linear: one wave = 4 tiles = 64 nodes (B frags reused) ----
    const int wave = threadIdx.x >> 6, lane = threadIdx.x & 63;
    const int row = lane & 15, grp = lane >> 4;

    bf16x8 bf[4][4];
#pragma unroll
    for (int nt = 0; nt < 4; ++nt) {
        const float* wrow = fc_w + (size_t)(nt * 16 + row) * 128;
#pragma unroll
        for (int kb = 0; kb < 4; ++kb)
            bf[nt][kb] = pack8(wrow + kb * 32 + grp * 8);
    }
    float aw0[4], aw1[4];
#pragma unroll
    for (int nt = 0; nt < 4; ++nt) {
        aw0[nt] = a_w[nt * 16 + row];
        aw1[nt] = a_w[64 + nt * 16 + row];
    }
    const float ab = a_b[0];

    const int nbase = blockIdx.x * 256 + wave * 64;
    if (nbase >= N) return;

#pragma unroll
    for (int tt = 0; tt < 4; ++tt) {
        const int tbase = nbase + tt * 16;
        if (tbase >= N) break;
        const int node = min(tbase + row, N - 1);

        bf16x8 af[4];
#pragma unroll
        for (int kb = 0; kb < 4; ++kb)
            af[kb] = pack8(x + (size_t)node * 128 + kb * 32 + grp * 8);

        f32x4 acc[4];
#pragma unroll
        for (int nt = 0; nt < 4; ++nt) acc[nt] = (f32x4){0.f, 0.f, 0.f, 0.f};

#pragma unroll
        for (int nt = 0; nt < 4; ++nt)
#pragma unroll
            for (int kb = 0; kb < 4; ++kb)
                acc[nt] = __builtin_amdgcn_mfma_f32_16x16x32_bf16(
                    af[kb], bf[nt][kb], acc[nt], 0, 0, 0);

#pragma unroll
        for (int nt = 0; nt < 4; ++nt)
#pragma unroll
            for (int r = 0; r < 4; ++r) {
                int nrow = tbase + grp * 4 + r;
                if (nrow < N)
                    h0b[(size_t)nrow * 64 + nt * 16 + row] = f2bf(acc[nt][r]);
            }

#pragma unroll
        for (int r = 0; r < 4; ++r) {
            float p0 = 0.f, p1 = 0.f;
#pragma unroll
            for (int nt = 0; nt < 4; ++nt) {
                p0 += acc[nt][r] * aw0[nt];
                p1 += acc[nt][r] * aw1[nt];
            }
#pragma unroll
            for (int off = 1; off < 16; off <<= 1) {
                p0 += __shfl_xor(p0, off);
                p1 += __shfl_xor(p1, off);
            }
            int nrow = tbase + grp * 4 + r;
            if (row == 0 && nrow < N) { s_src[nrow] = p0 + ab; s_dst[nrow] = p1; }
        }
    }
}

// ---------------------------------------------------------------------------
// K2: column scan of Hist -> Base[seg][b] + coltot[b]   (NEB <= 512)
__global__ __launch_bounds__(512) void k_colscan(
    const int* __restrict__ Hist, int* __restrict__ Base,
    int* __restrict__ coltot, int NEB, int NB)
{
    __shared__ int wsum[8];
    const int b = blockIdx.x;
    const int t = threadIdx.x, wv = t >> 6, lane = t & 63;
    int v = (t < NEB) ? Hist[t * NB + b] : 0;
    int incl = wave_scan_incl(v, lane);
    if (lane == 63) wsum[wv] = incl;
    __syncthreads();
    int woff = 0;
    for (int w = 0; w < wv; ++w) woff += wsum[w];
    if (t < NEB) Base[t * NB + b] = woff + incl - v;
    if (t == NEB - 1) coltot[b] = woff + incl;
}

// ---------------------------------------------------------------------------
// K3: per-segment bin with DIRECT register->global placement (no staging).
// Each block scans coltot -> local boff (ordered regions); block 0 publishes
// boff for k_bucket. blockIdx -> seg via bijective XCD swizzle.
__global__ __launch_bounds__(512) void k_bin(
    const int* __restrict__ src, const int* __restrict__ dst,
    const float* __restrict__ adj,
    const float* __restrict__ s_src, const float* __restrict__ s_dst,
    const int* __restrict__ coltot, const int* __restrict__ Base,
    int* __restrict__ boff,
    int2* __restrict__ binned, unsigned short* __restrict__ h_bf,
    int E, int NB, int NEB)
{
    __shared__ int  hist[NBMAX];     // counts -> local prefix -> cursor
    __shared__ int  gbase[NBMAX];    // lboff, then global write base per bucket
    __shared__ int  wpart[8];

    const int t = threadIdx.x;
    const int seg = xcd_swz(blockIdx.x, NEB);
    const int e0 = seg * EPB;
    const int lane = t & 63, wv = t >> 6;
    const int C = (NB + 511) / 512;  // 4 at NB=1563

    // ---- phase 0: scan coltot -> lboff (into gbase); block 0 -> boff ----
    {
        const int lo = t * C, hiB = min(NB, lo + C);
        int cv[4];
        int ssum = 0;
        for (int b = lo; b < hiB; ++b) { cv[b - lo] = coltot[b]; ssum += cv[b - lo]; }
        int incl = wave_scan_incl(ssum, lane);
        if (lane == 63) wpart[wv] = incl;
        __syncthreads();
        int woff = 0;
        for (int w2 = 0; w2 < wv; ++w2) woff += wpart[w2];
        int run = woff + incl - ssum;
        for (int b = lo; b < hiB; ++b) { gbase[b] = run; run += cv[b - lo]; }
        __syncthreads();
        if (blockIdx.x == 0)
            for (int b = t; b < NB; b += 512) boff[b] = gbase[b];
    }

    for (int b = t; b < NB; b += 512) hist[b] = 0;
    __syncthreads();

    // load 8 edges/thread, build records, LDS histogram, persist h_bf
    int rw0[8], rw1[8], bkt[8];
#pragma unroll
    for (int k = 0; k < 2; ++k) {
        int e = e0 + k * 2048 + t * 4;
        if (e + 3 < E) {
            int4   s4 = *(const int4*)&src[e];
            int4   d4 = *(const int4*)&dst[e];
            float4 a4 = *(const float4*)&adj[e];
            ushort4 hb;
#pragma unroll
            for (int q = 0; q < 4; ++q) {
                const int i = k * 4 + q;
                int s = (&s4.x)[q], d = (&d4.x)[q];
                float h = leaky_exp(s_src[s] + s_dst[d]);
                float v = h * (&a4.x)[q];
                unsigned short hb16 = f2bf(h);
                (&hb.x)[q] = hb16;
                rw0[i] = d | ((s & (BSZ - 1)) << 24);
                rw1[i] = (int)(((unsigned)hb16 << 16) | f2bf(v));
                bkt[i] = s >> BSH;
                atomicAdd(&hist[bkt[i]], 1);
            }
            *(ushort4*)&h_bf[e] = hb;
        } else {
#pragma unroll
            for (int q = 0; q < 4; ++q) {
                const int i = k * 4 + q;
                int ee = e + q;
                if (ee < E) {
                    int s = src[ee], d = dst[ee];
                    float h = leaky_exp(s_src[s] + s_dst[d]);
                    float v = h * adj[ee];
                    unsigned short hb16 = f2bf(h);
                    h_bf[ee] = hb16;
                    rw0[i] = d | ((s & (BSZ - 1)) << 24);
                    rw1[i] = (int)(((unsigned)hb16 << 16) | f2bf(v));
                    bkt[i] = s >> BSH;
                    atomicAdd(&hist[bkt[i]], 1);
                } else bkt[i] = -1;
            }
        }
    }
    __syncthreads();

    // block exclusive scan of hist[0..NB) in place (512 threads)
    {
        const int lo = t * C, hiB = min(NB, lo + C);
        int ssum = 0;
        for (int b = lo; b < hiB; ++b) ssum += hist[b];
        int incl = wave_scan_incl(ssum, lane);
        if (lane == 63) wpart[wv] = incl;
        __syncthreads();
        int woff = 0;
        for (int w2 = 0; w2 < wv; ++w2) woff += wpart[w2];
        int run = woff + incl - ssum;
        for (int b = lo; b < hiB; ++b) { int v = hist[b]; hist[b] = run; run += v; }
        __syncthreads();
    }

    // global write base per bucket (hist keeps lpref and becomes the cursor)
    for (int b = t; b < NB; b += 512)
        gbase[b] = gbase[b] + Base[seg * NB + b] - hist[b];
    __syncthreads();

    // direct placement: pos within block via LDS cursor; write from registers.
    // (same-XCD L2 merges partial lines; order within block irrelevant.)
#pragma unroll
    for (int i = 0; i < 8; ++i) {
        if (bkt[i] >= 0) {
            int pos = atomicAdd(&hist[bkt[i]], 1);
            binned[gbase[bkt[i]] + pos] = make_int2(rw0[i], rw1[i]);
        }
    }
}

// ---------------------------------------------------------------------------
// K4: per-bucket contiguous records -> LDS CSR + dual-node quad-gather.
// h packed in rec.y; h-sum folded into the shfl-reduce (no LDS float atomics).
__global__ __launch_bounds__(256) void k_bucket(
    const int2* __restrict__ binned, const int* __restrict__ boff,
    const int* __restrict__ coltot,
    const unsigned short* __restrict__ h0b, float* __restrict__ out,
    float* __restrict__ inv_hsum_g, int N)
{
    __shared__ int   deg_cur[BSZ];
    __shared__ int   pref[BSZ + 1];
    __shared__ int2  rec[CAPB];       // {dst, h_bf<<16 | v_bf}

    const int b   = blockIdx.x;
    const int lo  = boff[b];
    const int cnt = coltot[b];
    const int hi  = lo + cnt;
    const int n0 = b << BSH;
    const int nn = min(BSZ, N - n0);
    const int t = threadIdx.x, wv = t >> 6, lane = t & 63;

    if (t < BSZ) deg_cur[t] = 0;
    __syncthreads();

    if (cnt <= CAPB) {
        int2 r[MAXIT];
#pragma unroll
        for (int it = 0; it < MAXIT; ++it) {
            int j = lo + it * 256 + t;
            if (j < hi) r[it] = binned[j];
        }
#pragma unroll
        for (int it = 0; it < MAXIT; ++it)
            if (lo + it * 256 + t < hi)
                atomicAdd(&deg_cur[(unsigned)r[it].x >> 24], 1);
        __syncthreads();

        // single-wave scan over 64 degrees
        if (wv == 0) {
            int v = deg_cur[lane];
            int incl = wave_scan_incl(v, lane);
            pref[lane + 1] = incl;
            if (lane == 0) pref[0] = 0;
            deg_cur[lane] = incl - v;        // cursor = exclusive prefix
        }
        __syncthreads();

#pragma unroll
        for (int it = 0; it < MAXIT; ++it) {
            if (lo + it * 256 + t < hi) {
                int2 rr = r[it];
                int node = (unsigned)rr.x >> 24;
                int pos = atomicAdd(&deg_cur[node], 1);
                rec[pos] = make_int2(rr.x & 0xFFFFFF, rr.y);
            }
        }
        __syncthreads();

        // dual-node quad-gather: wave handles (nA, nA+4); h-sum in-reduce
        const int eslot = lane >> 4, fq = lane & 15;
        for (int nA = wv; nA < nn; nA += 8) {
            const int nB = nA + 4;
            const bool hasB = (nB < nn);
            const int sA = pref[nA], eA2 = pref[nA + 1];
            const int sB = hasB ? pref[nB] : 0, eB2 = hasB ? pref[nB + 1] : 0;

            float aA[4] = {0.f, 0.f, 0.f, 0.f}, bA[4] = {0.f, 0.f, 0.f, 0.f};
            float aB[4] = {0.f, 0.f, 0.f, 0.f}, bB[4] = {0.f, 0.f, 0.f, 0.f};
            float hA = 0.f, hB = 0.f;

            const int roundsA = (eA2 - sA + 7) >> 3;
            const int roundsB = (eB2 - sB + 7) >> 3;
            const int rounds  = max(roundsA, roundsB);

            for (int rr2 = 0; rr2 < rounds; ++rr2) {
                const int bA2 = sA + rr2 * 8;
                const int bB2 = sB + rr2 * 8;
                int idxA0 = bA2 + eslot,     idxA1 = bA2 + 4 + eslot;
                int idxB0 = bB2 + eslot,     idxB1 = bB2 + 4 + eslot;
                bool vA0 = idxA0 < eA2, vA1 = idxA1 < eA2;
                bool vB0 = hasB && idxB0 < eB2, vB1 = hasB && idxB1 < eB2;
                int2 rA0 = rec[vA0 ? idxA0 : 0];
                int2 rA1 = rec[vA1 ? idxA1 : 0];
                int2 rB0 = rec[vB0 ? idxB0 : 0];
                int2 rB1 = rec[vB1 ? idxB1 : 0];
                float valA0 = vA0 ? __uint_as_float((unsigned)rA0.y << 16) : 0.f;
                float valA1 = vA1 ? __uint_as_float((unsigned)rA1.y << 16) : 0.f;
                float valB0 = vB0 ? __uint_as_float((unsigned)rB0.y << 16) : 0.f;
                float valB1 = vB1 ? __uint_as_float((unsigned)rB1.y << 16) : 0.f;
                hA += (vA0 ? __uint_as_float((unsigned)rA0.y & 0xFFFF0000u) : 0.f)
                    + (vA1 ? __uint_as_float((unsigned)rA1.y & 0xFFFF0000u) : 0.f);
                hB += (vB0 ? __uint_as_float((unsigned)rB0.y & 0xFFFF0000u) : 0.f)
                    + (vB1 ? __uint_as_float((unsigned)rB1.y & 0xFFFF0000u) : 0.f);
                uint2 uA0 = *(const uint2*)(h0b + (size_t)rA0.x * 64 + fq * 4);
                uint2 uA1 = *(const uint2*)(h0b + (size_t)rA1.x * 64 + fq * 4);
                uint2 uB0 = *(const uint2*)(h0b + (size_t)rB0.x * 64 + fq * 4);
                uint2 uB1 = *(const uint2*)(h0b + (size_t)rB1.x * 64 + fq * 4);
                aA[0] += valA0 * __uint_as_float(uA0.x << 16);
                aA[1] += valA0 * __uint_as_float(uA0.x & 0xFFFF0000u);
                aA[2] += valA0 * __uint_as_float(uA0.y << 16);
                aA[3] += valA0 * __uint_as_float(uA0.y & 0xFFFF0000u);
                bA[0] += valA1 * __uint_as_float(uA1.x << 16);
                bA[1] += valA1 * __uint_as_float(uA1.x & 0xFFFF0000u);
                bA[2] += valA1 * __uint_as_float(uA1.y << 16);
                bA[3] += valA1 * __uint_as_float(uA1.y & 0xFFFF0000u);
                aB[0] += valB0 * __uint_as_float(uB0.x << 16);
                aB[1] += valB0 * __uint_as_float(uB0.x & 0xFFFF0000u);
                aB[2] += valB0 * __uint_as_float(uB0.y << 16);
                aB[3] += valB0 * __uint_as_float(uB0.y & 0xFFFF0000u);
                bB[0] += valB1 * __uint_as_float(uB1.x << 16);
                bB[1] += valB1 * __uint_as_float(uB1.x & 0xFFFF0000u);
                bB[2] += valB1 * __uint_as_float(uB1.y << 16);
                bB[3] += valB1 * __uint_as_float(uB1.y & 0xFFFF0000u);
            }

#pragma unroll
            for (int k = 0; k < 4; ++k) {
                float vv = aA[k] + bA[k];
                vv += __shfl_xor(vv, 16);
                vv += __shfl_xor(vv, 32);
                aA[k] = vv;
                float ww = aB[k] + bB[k];
                ww += __shfl_xor(ww, 16);
                ww += __shfl_xor(ww, 32);
                aB[k] = ww;
            }
            hA += __shfl_xor(hA, 16);
            hA += __shfl_xor(hA, 32);
            hB += __shfl_xor(hB, 16);
            hB += __shfl_xor(hB, 32);

            const float invA = (eA2 > sA) ? 1.0f / hA : 0.f;
            const float invB = (hasB && eB2 > sB) ? 1.0f / hB : 0.f;
            if (lane < 16) {
                float4 o;
                o.x = aA[0] * invA; o.y = aA[1] * invA;
                o.z = aA[2] * invA; o.w = aA[3] * invA;
                *(float4*)&out[(size_t)(n0 + nA) * 64 + fq * 4] = o;
            } else if (hasB && lane < 32) {
                float4 o;
                o.x = aB[0] * invB; o.y = aB[1] * invB;
                o.z = aB[2] * invB; o.w = aB[3] * invB;
                *(float4*)&out[(size_t)(n0 + nB) * 64 + fq * 4] = o;
            }
            if (lane == 0) inv_hsum_g[n0 + nA] = invA;
            if (hasB && lane == 16) inv_hsum_g[n0 + nB] = invB;
        }
    } else {
        // correctness-only fallback (cnt > CAPB is ~16 sigma; never expected)
        for (int n = wv; n < nn; n += 4) {
            float acc = 0.f, hs = 0.f;
            for (int j = lo; j < hi; ++j) {
                int2 rr = binned[j];
                if (((unsigned)rr.x >> 24) == (unsigned)n) {
                    hs  += __uint_as_float((unsigned)rr.y & 0xFFFF0000u);
                    acc += __uint_as_float((unsigned)rr.y << 16) *
                           bf2f(h0b[(size_t)(rr.x & 0xFFFFFF) * 64 + lane]);
                }
            }
            float inv = (hs > 0.f) ? 1.0f / hs : 0.f;
            out[(size_t)(n0 + n) * 64 + lane] = acc * inv;
            if (lane == 0) inv_hsum_g[n0 + n] = inv;
        }
    }
}

// ---------------------------------------------------------------------------
// K5: alpha[e] = h_bf[e] * inv_hsum[src[e]]  (pure stream, x4)
__global__ __launch_bounds__(256) void k_alpha(
    const int* __restrict__ src, const unsigned short* __restrict__ h_bf,
    const float* __restrict__ inv_hsum_g, float* __restrict__ alpha, int E)
{
    int i = blockIdx.x * 256 + threadIdx.x;
    int e = i * 4;
    if (e + 3 < E) {
        ushort4 hb = *(const ushort4*)&h_bf[e];
        int4 s4 = *(const int4*)&src[e];
        float4 a;
        a.x = bf2f(hb.x) * inv_hsum_g[s4.x];
        a.y = bf2f(hb.y) * inv_hsum_g[s4.y];
        a.z = bf2f(hb.z) * inv_hsum_g[s4.z];
        a.w = bf2f(hb.w) * inv_hsum_g[s4.w];
        *(float4*)&alpha[e] = a;
    } else {
        for (; e < E; ++e)
            alpha[e] = bf2f(h_bf[e]) * inv_hsum_g[src[e]];
    }
}

// ---------------------------------------------------------------------------
extern "C" void kernel_launch(void* const* d_in, const int* in_sizes, int n_in,
                              void* d_out, int out_size, void* d_ws, size_t ws_size,
                              hipStream_t stream)
{
    const float* x    = (const float*)d_in[0];
    const int*   ei   = (const int*)d_in[1];
    const float* adj  = (const float*)d_in[2];
    const float* fc_w = (const float*)d_in[3];
    const float* a_w  = (const float*)d_in[4];
    const float* a_b  = (const float*)d_in[5];

    const int N = in_sizes[0] / 128;          // 100000
    const int E = in_sizes[2];                // 1600000
    const int* src = ei;
    const int* dst = ei + E;

    const int NB  = (N + BSZ - 1) >> BSH;     // 1563 buckets
    const int NEB = (E + EPB - 1) / EPB;      // 391 segments

    float* out   = (float*)d_out;
    float* alpha = out + (size_t)N * 64;

    char* w = (char*)d_ws;
    auto carve = [&](size_t bytes) {
        char* p = w;
        w += (bytes + 255) & ~(size_t)255;
        return p;
    };
    unsigned short* h0b  = (unsigned short*)carve((size_t)N * 64 * 2);
    float* s_src   = (float*)carve((size_t)N * 4);
    float* s_dst   = (float*)carve((size_t)N * 4);
    float* inv_hs  = (float*)carve((size_t)N * 4);
    unsigned short* h_bf = (unsigned short*)carve((size_t)E * 2);
    int*   Hist    = (int*)  carve((size_t)NEB * NB * 4);
    int*   Base    = (int*)  carve((size_t)NEB * NB * 4);
    int*   coltot  = (int*)  carve((size_t)NB * 4);
    int*   boff    = (int*)  carve((size_t)NB * 4);
    int2*  binned  = (int2*) carve((size_t)E * 8);

    const int lgrid = (N + 255) / 256;         // 391 linear blocks (4 tiles/wave)

    k_linear_hist<<<lgrid + NEB, 256, 0, stream>>>(
        x, fc_w, a_w, a_b, h0b, s_src, s_dst, src, Hist, N, E, NB, lgrid);
    k_colscan<<<NB, 512, 0, stream>>>(Hist, Base, coltot, NEB, NB);
    k_bin<<<NEB, 512, 0, stream>>>(src, dst, adj, s_src, s_dst, coltot, Base,
                                   boff, binned, h_bf, E, NB, NEB);
    k_bucket<<<NB, 256, 0, stream>>>(binned, boff, coltot, h0b, out, inv_hs, N);
    k_alpha<<<(E / 4 + 255) / 256, 256, 0, stream>>>(src, h_bf, inv_hs, alpha, E);
}

// Round 23
// 109.583 us; speedup vs baseline: 1.1284x; 1.0326x over previous
//
#include <hip/hip_runtime.h>
#include <hip/hip_bf16.h>

// GAT layer, round 23: REVERT to round-20 configuration (109.7us, best).
// r21 (BSZ=32) and r22 (destaged k_bin) both regressed; r20's staged,
// ordered-write producer at NB=1563 + 4-tile MFMA linear + h-fold bucket
// is the measured local optimum from three directions.
// N=100000, F=128, H=64, E=1.6M.

#define LEAKY 0.05f
#define BSH   6                  // nodes per bucket = 64
#define BSZ   64
#define EPB   4096               // edges per segment
#define MAXIT 6
#define CAPB  (MAXIT * 256)      // 1536 cap (mean 1023, +16 sigma)
#define NBMAX 2048               // NB = 1563
#define NXCD  8

using bf16x8 = __attribute__((ext_vector_type(8))) __bf16;
using f32x4  = __attribute__((ext_vector_type(4))) float;

__device__ __forceinline__ int wave_scan_incl(int v, int lane) {
#pragma unroll
    for (int off = 1; off < 64; off <<= 1) {
        int u = __shfl_up(v, off);
        if (lane >= off) v += u;
    }
    return v;
}
__device__ __forceinline__ unsigned short f2bf(float f) {   // RNE bf16
    unsigned u = __float_as_uint(f);
    return (unsigned short)((u + 0x7FFF + ((u >> 16) & 1)) >> 16);
}
__device__ __forceinline__ float bf2f(unsigned short u) {
    return __uint_as_float((unsigned)u << 16);
}
__device__ __forceinline__ bf16x8 pack8(const float* p) {
    float4 lo = *(const float4*)p;
    float4 hi = *(const float4*)(p + 4);
    bf16x8 v;
    v[0] = (__bf16)lo.x; v[1] = (__bf16)lo.y; v[2] = (__bf16)lo.z; v[3] = (__bf16)lo.w;
    v[4] = (__bf16)hi.x; v[5] = (__bf16)hi.y; v[6] = (__bf16)hi.z; v[7] = (__bf16)hi.w;
    return v;
}
__device__ __forceinline__ float leaky_exp(float t) {
    t = (t >= 0.f) ? t : LEAKY * t;
    return __expf(t);
}
// bijective XCD swizzle (m204): consecutive logical ids on same XCD
__device__ __forceinline__ int xcd_swz(int i, int n) {
    int q = n / NXCD, r = n % NXCD;
    int xcd = i % NXCD, j = i / NXCD;
    return (xcd < r) ? xcd * (q + 1) + j : r * (q + 1) + (xcd - r) * q + j;
}

// ---------------------------------------------------------------------------
// K1 (fused): blocks [0,lgrid) -> MFMA linear (4 tiles/wave); rest -> histogram.
__global__ __launch_bounds__(256) void k_linear_hist(
    const float* __restrict__ x, const float* __restrict__ fc_w,
    const float* __restrict__ a_w, const float* __restrict__ a_b,
    unsigned short* __restrict__ h0b, float* __restrict__ s_src,
    float* __restrict__ s_dst,
    const int* __restrict__ src, int* __restrict__ Hist,
    int N, int E, int NB, int lgrid)
{
    __shared__ int hist[NBMAX];

    if (blockIdx.x >= lgrid) {
        const int seg = blockIdx.x - lgrid;
        for (int b = threadIdx.x; b < NB; b += 256) hist[b] = 0;
        __syncthreads();
        const int e0 = seg * EPB;
#pragma unroll
        for (int k = 0; k < EPB / 1024; ++k) {
            int e = e0 + k * 1024 + threadIdx.x * 4;
            if (e + 3 < E) {
                int4 s4 = *(const int4*)&src[e];
                atomicAdd(&hist[s4.x >> BSH], 1);
                atomicAdd(&hist[s4.y >> BSH], 1);
                atomicAdd(&hist[s4.z >> BSH], 1);
                atomicAdd(&hist[s4.w >> BSH], 1);
            } else {
                for (int q = e; q < E; ++q) atomicAdd(&hist[src[q] >> BSH], 1);
            }
        }
        __syncthreads();
        for (int b = threadIdx.x; b < NB; b += 256)
            Hist[seg * NB + b] = hist[b];
        return;
    }

    // ---- MFMA linear: one wave = 4 tiles = 64 nodes (B frags reused) ----
    const int wave = threadIdx.x >> 6, lane = threadIdx.x & 63;
    const int row = lane & 15, grp = lane >> 4;

    bf16x8 bf[4][4];
#pragma unroll
    for (int nt = 0; nt < 4; ++nt) {
        const float* wrow = fc_w + (size_t)(nt * 16 + row) * 128;
#pragma unroll
        for (int kb = 0; kb < 4; ++kb)
            bf[nt][kb] = pack8(wrow + kb * 32 + grp * 8);
    }
    float aw0[4], aw1[4];
#pragma unroll
    for (int nt = 0; nt < 4; ++nt) {
        aw0[nt] = a_w[nt * 16 + row];
        aw1[nt] = a_w[64 + nt * 16 + row];
    }
    const float ab = a_b[0];

    const int nbase = blockIdx.x * 256 + wave * 64;
    if (nbase >= N) return;

#pragma unroll
    for (int tt = 0; tt < 4; ++tt) {
        const int tbase = nbase + tt * 16;
        if (tbase >= N) break;
        const int node = min(tbase + row, N - 1);

        bf16x8 af[4];
#pragma unroll
        for (int kb = 0; kb < 4; ++kb)
            af[kb] = pack8(x + (size_t)node * 128 + kb * 32 + grp * 8);

        f32x4 acc[4];
#pragma unroll
        for (int nt = 0; nt < 4; ++nt) acc[nt] = (f32x4){0.f, 0.f, 0.f, 0.f};

#pragma unroll
        for (int nt = 0; nt < 4; ++nt)
#pragma unroll
            for (int kb = 0; kb < 4; ++kb)
                acc[nt] = __builtin_amdgcn_mfma_f32_16x16x32_bf16(
                    af[kb], bf[nt][kb], acc[nt], 0, 0, 0);

#pragma unroll
        for (int nt = 0; nt < 4; ++nt)
#pragma unroll
            for (int r = 0; r < 4; ++r) {
                int nrow = tbase + grp * 4 + r;
                if (nrow < N)
                    h0b[(size_t)nrow * 64 + nt * 16 + row] = f2bf(acc[nt][r]);
            }

#pragma unroll
        for (int r = 0; r < 4; ++r) {
            float p0 = 0.f, p1 = 0.f;
#pragma unroll
            for (int nt = 0; nt < 4; ++nt) {
                p0 += acc[nt][r] * aw0[nt];
                p1 += acc[nt][r] * aw1[nt];
            }
#pragma unroll
            for (int off = 1; off < 16; off <<= 1) {
                p0 += __shfl_xor(p0, off);
                p1 += __shfl_xor(p1, off);
            }
            int nrow = tbase + grp * 4 + r;
            if (row == 0 && nrow < N) { s_src[nrow] = p0 + ab; s_dst[nrow] = p1; }
        }
    }
}

// ---------------------------------------------------------------------------
// K2: column scan of Hist -> Base[seg][b] + coltot[b]   (NEB <= 512)
__global__ __launch_bounds__(512) void k_colscan(
    const int* __restrict__ Hist, int* __restrict__ Base,
    int* __restrict__ coltot, int NEB, int NB)
{
    __shared__ int wsum[8];
    const int b = blockIdx.x;
    const int t = threadIdx.x, wv = t >> 6, lane = t & 63;
    int v = (t < NEB) ? Hist[t * NB + b] : 0;
    int incl = wave_scan_incl(v, lane);
    if (lane == 63) wsum[wv] = incl;
    __syncthreads();
    int woff = 0;
    for (int w = 0; w < wv; ++w) woff += wsum[w];
    if (t < NEB) Base[t * NB + b] = woff + incl - v;
    if (t == NEB - 1) coltot[b] = woff + incl;
}

// ---------------------------------------------------------------------------
// K3: per-segment LDS sort + ORDERED global placement; streams h (bf16).
// Each block scans coltot -> local boff (ordered regions); block 0 publishes
// boff for k_bucket. blockIdx -> seg via bijective XCD swizzle.
__global__ __launch_bounds__(512) void k_bin(
    const int* __restrict__ src, const int* __restrict__ dst,
    const float* __restrict__ adj,
    const float* __restrict__ s_src, const float* __restrict__ s_dst,
    const int* __restrict__ coltot, const int* __restrict__ Base,
    int* __restrict__ boff,
    int2* __restrict__ binned, unsigned short* __restrict__ h_bf,
    int E, int NB, int NEB)
{
    __shared__ int  hist[NBMAX];     // counts -> local prefix -> cursor
    __shared__ int  gbase[NBMAX];    // lboff, then global base per bucket
    __shared__ int  wpart[8];
    __shared__ int2 stage[EPB];      // 32 KB
    __shared__ int  gaddr[EPB];      // 16 KB

    const int t = threadIdx.x;
    const int seg = xcd_swz(blockIdx.x, NEB);
    const int e0 = seg * EPB;
    const int segcnt = min(EPB, E - e0);
    const int lane = t & 63, wv = t >> 6;
    const int C = (NB + 511) / 512;  // 4 at NB=1563

    // ---- phase 0: scan coltot -> lboff (into gbase); block 0 -> boff ----
    {
        const int lo = t * C, hiB = min(NB, lo + C);
        int cv[4];
        int ssum = 0;
        for (int b = lo; b < hiB; ++b) { cv[b - lo] = coltot[b]; ssum += cv[b - lo]; }
        int incl = wave_scan_incl(ssum, lane);
        if (lane == 63) wpart[wv] = incl;
        __syncthreads();
        int woff = 0;
        for (int w2 = 0; w2 < wv; ++w2) woff += wpart[w2];
        int run = woff + incl - ssum;
        for (int b = lo; b < hiB; ++b) { gbase[b] = run; run += cv[b - lo]; }
        __syncthreads();
        if (blockIdx.x == 0)
            for (int b = t; b < NB; b += 512) boff[b] = gbase[b];
    }

    for (int b = t; b < NB; b += 512) hist[b] = 0;
    __syncthreads();

    // load 8 edges/thread, build records, LDS histogram, persist h_bf
    int rw0[8], rw1[8], bkt[8];
#pragma unroll
    for (int k = 0; k < 2; ++k) {
        int e = e0 + k * 2048 + t * 4;
        if (e + 3 < E) {
            int4   s4 = *(const int4*)&src[e];
            int4   d4 = *(const int4*)&dst[e];
            float4 a4 = *(const float4*)&adj[e];
            ushort4 hb;
#pragma unroll
            for (int q = 0; q < 4; ++q) {
                const int i = k * 4 + q;
                int s = (&s4.x)[q], d = (&d4.x)[q];
                float h = leaky_exp(s_src[s] + s_dst[d]);
                float v = h * (&a4.x)[q];
                unsigned short hb16 = f2bf(h);
                (&hb.x)[q] = hb16;
                rw0[i] = d | ((s & (BSZ - 1)) << 24);
                rw1[i] = (int)(((unsigned)hb16 << 16) | f2bf(v));
                bkt[i] = s >> BSH;
                atomicAdd(&hist[bkt[i]], 1);
            }
            *(ushort4*)&h_bf[e] = hb;
        } else {
#pragma unroll
            for (int q = 0; q < 4; ++q) {
                const int i = k * 4 + q;
                int ee = e + q;
                if (ee < E) {
                    int s = src[ee], d = dst[ee];
                    float h = leaky_exp(s_src[s] + s_dst[d]);
                    float v = h * adj[ee];
                    unsigned short hb16 = f2bf(h);
                    h_bf[ee] = hb16;
                    rw0[i] = d | ((s & (BSZ - 1)) << 24);
                    rw1[i] = (int)(((unsigned)hb16 << 16) | f2bf(v));
                    bkt[i] = s >> BSH;
                    atomicAdd(&hist[bkt[i]], 1);
                } else bkt[i] = -1;
            }
        }
    }
    __syncthreads();

    // block exclusive scan of hist[0..NB) in place (512 threads)
    {
        const int lo = t * C, hiB = min(NB, lo + C);
        int ssum = 0;
        for (int b = lo; b < hiB; ++b) ssum += hist[b];
        int incl = wave_scan_incl(ssum, lane);
        if (lane == 63) wpart[wv] = incl;
        __syncthreads();
        int woff = 0;
        for (int w2 = 0; w2 < wv; ++w2) woff += wpart[w2];
        int run = woff + incl - ssum;
        for (int b = lo; b < hiB; ++b) { int v = hist[b]; hist[b] = run; run += v; }
        __syncthreads();
    }

    // global base per bucket (hist keeps lpref and becomes the cursor)
    for (int b = t; b < NB; b += 512)
        gbase[b] = gbase[b] + Base[seg * NB + b] - hist[b];
    __syncthreads();

    // place records into sorted LDS slots + record their global address
#pragma unroll
    for (int i = 0; i < 8; ++i) {
        if (bkt[i] >= 0) {
            int pos = atomicAdd(&hist[bkt[i]], 1);
            stage[pos] = make_int2(rw0[i], rw1[i]);
            gaddr[pos] = gbase[bkt[i]] + pos;
        }
    }
    __syncthreads();

    // ordered write-out: consecutive j -> monotone ascending gaddr
    for (int j = t; j < segcnt; j += 512)
        binned[gaddr[j]] = stage[j];
}

// ---------------------------------------------------------------------------
// K4: per-bucket contiguous records -> LDS CSR + dual-node quad-gather.
// h packed in rec.y; h-sum folded into the shfl-reduce (no LDS float atomics).
__global__ __launch_bounds__(256) void k_bucket(
    const int2* __restrict__ binned, const int* __restrict__ boff,
    const int* __restrict__ coltot,
    const unsigned short* __restrict__ h0b, float* __restrict__ out,
    float* __restrict__ inv_hsum_g, int N)
{
    __shared__ int   deg_cur[BSZ];
    __shared__ int   pref[BSZ + 1];
    __shared__ int2  rec[CAPB];       // {dst, h_bf<<16 | v_bf}

    const int b   = blockIdx.x;
    const int lo  = boff[b];
    const int cnt = coltot[b];
    const int hi  = lo + cnt;
    const int n0 = b << BSH;
    const int nn = min(BSZ, N - n0);
    const int t = threadIdx.x, wv = t >> 6, lane = t & 63;

    if (t < BSZ) deg_cur[t] = 0;
    __syncthreads();

    if (cnt <= CAPB) {
        int2 r[MAXIT];
#pragma unroll
        for (int it = 0; it < MAXIT; ++it) {
            int j = lo + it * 256 + t;
            if (j < hi) r[it] = binned[j];
        }
#pragma unroll
        for (int it = 0; it < MAXIT; ++it)
            if (lo + it * 256 + t < hi)
                atomicAdd(&deg_cur[(unsigned)r[it].x >> 24], 1);
        __syncthreads();

        // single-wave scan over 64 degrees
        if (wv == 0) {
            int v = deg_cur[lane];
            int incl = wave_scan_incl(v, lane);
            pref[lane + 1] = incl;
            if (lane == 0) pref[0] = 0;
            deg_cur[lane] = incl - v;        // cursor = exclusive prefix
        }
        __syncthreads();

#pragma unroll
        for (int it = 0; it < MAXIT; ++it) {
            if (lo + it * 256 + t < hi) {
                int2 rr = r[it];
                int node = (unsigned)rr.x >> 24;
                int pos = atomicAdd(&deg_cur[node], 1);
                rec[pos] = make_int2(rr.x & 0xFFFFFF, rr.y);
            }
        }
        __syncthreads();

        // dual-node quad-gather: wave handles (nA, nA+4); h-sum in-reduce
        const int eslot = lane >> 4, fq = lane & 15;
        for (int nA = wv; nA < nn; nA += 8) {
            const int nB = nA + 4;
            const bool hasB = (nB < nn);
            const int sA = pref[nA], eA2 = pref[nA + 1];
            const int sB = hasB ? pref[nB] : 0, eB2 = hasB ? pref[nB + 1] : 0;

            float aA[4] = {0.f, 0.f, 0.f, 0.f}, bA[4] = {0.f, 0.f, 0.f, 0.f};
            float aB[4] = {0.f, 0.f, 0.f, 0.f}, bB[4] = {0.f, 0.f, 0.f, 0.f};
            float hA = 0.f, hB = 0.f;

            const int roundsA = (eA2 - sA + 7) >> 3;
            const int roundsB = (eB2 - sB + 7) >> 3;
            const int rounds  = max(roundsA, roundsB);

            for (int rr2 = 0; rr2 < rounds; ++rr2) {
                const int bA2 = sA + rr2 * 8;
                const int bB2 = sB + rr2 * 8;
                int idxA0 = bA2 + eslot,     idxA1 = bA2 + 4 + eslot;
                int idxB0 = bB2 + eslot,     idxB1 = bB2 + 4 + eslot;
                bool vA0 = idxA0 < eA2, vA1 = idxA1 < eA2;
                bool vB0 = hasB && idxB0 < eB2, vB1 = hasB && idxB1 < eB2;
                int2 rA0 = rec[vA0 ? idxA0 : 0];
                int2 rA1 = rec[vA1 ? idxA1 : 0];
                int2 rB0 = rec[vB0 ? idxB0 : 0];
                int2 rB1 = rec[vB1 ? idxB1 : 0];
                float valA0 = vA0 ? __uint_as_float((unsigned)rA0.y << 16) : 0.f;
                float valA1 = vA1 ? __uint_as_float((unsigned)rA1.y << 16) : 0.f;
                float valB0 = vB0 ? __uint_as_float((unsigned)rB0.y << 16) : 0.f;
                float valB1 = vB1 ? __uint_as_float((unsigned)rB1.y << 16) : 0.f;
                hA += (vA0 ? __uint_as_float((unsigned)rA0.y & 0xFFFF0000u) : 0.f)
                    + (vA1 ? __uint_as_float((unsigned)rA1.y & 0xFFFF0000u) : 0.f);
                hB += (vB0 ? __uint_as_float((unsigned)rB0.y & 0xFFFF0000u) : 0.f)
                    + (vB1 ? __uint_as_float((unsigned)rB1.y & 0xFFFF0000u) : 0.f);
                uint2 uA0 = *(const uint2*)(h0b + (size_t)rA0.x * 64 + fq * 4);
                uint2 uA1 = *(const uint2*)(h0b + (size_t)rA1.x * 64 + fq * 4);
                uint2 uB0 = *(const uint2*)(h0b + (size_t)rB0.x * 64 + fq * 4);
                uint2 uB1 = *(const uint2*)(h0b + (size_t)rB1.x * 64 + fq * 4);
                aA[0] += valA0 * __uint_as_float(uA0.x << 16);
                aA[1] += valA0 * __uint_as_float(uA0.x & 0xFFFF0000u);
                aA[2] += valA0 * __uint_as_float(uA0.y << 16);
                aA[3] += valA0 * __uint_as_float(uA0.y & 0xFFFF0000u);
                bA[0] += valA1 * __uint_as_float(uA1.x << 16);
                bA[1] += valA1 * __uint_as_float(uA1.x & 0xFFFF0000u);
                bA[2] += valA1 * __uint_as_float(uA1.y << 16);
                bA[3] += valA1 * __uint_as_float(uA1.y & 0xFFFF0000u);
                aB[0] += valB0 * __uint_as_float(uB0.x << 16);
                aB[1] += valB0 * __uint_as_float(uB0.x & 0xFFFF0000u);
                aB[2] += valB0 * __uint_as_float(uB0.y << 16);
                aB[3] += valB0 * __uint_as_float(uB0.y & 0xFFFF0000u);
                bB[0] += valB1 * __uint_as_float(uB1.x << 16);
                bB[1] += valB1 * __uint_as_float(uB1.x & 0xFFFF0000u);
                bB[2] += valB1 * __uint_as_float(uB1.y << 16);
                bB[3] += valB1 * __uint_as_float(uB1.y & 0xFFFF0000u);
            }

#pragma unroll
            for (int k = 0; k < 4; ++k) {
                float vv = aA[k] + bA[k];
                vv += __shfl_xor(vv, 16);
                vv += __shfl_xor(vv, 32);
                aA[k] = vv;
                float ww = aB[k] + bB[k];
                ww += __shfl_xor(ww, 16);
                ww += __shfl_xor(ww, 32);
                aB[k] = ww;
            }
            hA += __shfl_xor(hA, 16);
            hA += __shfl_xor(hA, 32);
            hB += __shfl_xor(hB, 16);
            hB += __shfl_xor(hB, 32);

            const float invA = (eA2 > sA) ? 1.0f / hA : 0.f;
            const float invB = (hasB && eB2 > sB) ? 1.0f / hB : 0.f;
            if (lane < 16) {
                float4 o;
                o.x = aA[0] * invA; o.y = aA[1] * invA;
                o.z = aA[2] * invA; o.w = aA[3] * invA;
                *(float4*)&out[(size_t)(n0 + nA) * 64 + fq * 4] = o;
            } else if (hasB && lane < 32) {
                float4 o;
                o.x = aB[0] * invB; o.y = aB[1] * invB;
                o.z = aB[2] * invB; o.w = aB[3] * invB;
                *(float4*)&out[(size_t)(n0 + nB) * 64 + fq * 4] = o;
            }
            if (lane == 0) inv_hsum_g[n0 + nA] = invA;
            if (hasB && lane == 16) inv_hsum_g[n0 + nB] = invB;
        }
    } else {
        // correctness-only fallback (cnt > CAPB is ~16 sigma; never expected)
        for (int n = wv; n < nn; n += 4) {
            float acc = 0.f, hs = 0.f;
            for (int j = lo; j < hi; ++j) {
                int2 rr = binned[j];
                if (((unsigned)rr.x >> 24) == (unsigned)n) {
                    hs  += __uint_as_float((unsigned)rr.y & 0xFFFF0000u);
                    acc += __uint_as_float((unsigned)rr.y << 16) *
                           bf2f(h0b[(size_t)(rr.x & 0xFFFFFF) * 64 + lane]);
                }
            }
            float inv = (hs > 0.f) ? 1.0f / hs : 0.f;
            out[(size_t)(n0 + n) * 64 + lane] = acc * inv;
            if (lane == 0) inv_hsum_g[n0 + n] = inv;
        }
    }
}

// ---------------------------------------------------------------------------
// K5: alpha[e] = h_bf[e] * inv_hsum[src[e]]  (pure stream, x4)
__global__ __launch_bounds__(256) void k_alpha(
    const int* __restrict__ src, const unsigned short* __restrict__ h_bf,
    const float* __restrict__ inv_hsum_g, float* __restrict__ alpha, int E)
{
    int i = blockIdx.x * 256 + threadIdx.x;
    int e = i * 4;
    if (e + 3 < E) {
        ushort4 hb = *(const ushort4*)&h_bf[e];
        int4 s4 = *(const int4*)&src[e];
        float4 a;
        a.x = bf2f(hb.x) * inv_hsum_g[s4.x];
        a.y = bf2f(hb.y) * inv_hsum_g[s4.y];
        a.z = bf2f(hb.z) * inv_hsum_g[s4.z];
        a.w = bf2f(hb.w) * inv_hsum_g[s4.w];
        *(float4*)&alpha[e] = a;
    } else {
        for (; e < E; ++e)
            alpha[e] = bf2f(h_bf[e]) * inv_hsum_g[src[e]];
    }
}

// ---------------------------------------------------------------------------
extern "C" void kernel_launch(void* const* d_in, const int* in_sizes, int n_in,
                              void* d_out, int out_size, void* d_ws, size_t ws_size,
                              hipStream_t stream)
{
    const float* x    = (const float*)d_in[0];
    const int*   ei   = (const int*)d_in[1];
    const float* adj  = (const float*)d_in[2];
    const float* fc_w = (const float*)d_in[3];
    const float* a_w  = (const float*)d_in[4];
    const float* a_b  = (const float*)d_in[5];

    const int N = in_sizes[0] / 128;          // 100000
    const int E = in_sizes[2];                // 1600000
    const int* src = ei;
    const int* dst = ei + E;

    const int NB  = (N + BSZ - 1) >> BSH;     // 1563 buckets
    const int NEB = (E + EPB - 1) / EPB;      // 391 segments

    float* out   = (float*)d_out;
    float* alpha = out + (size_t)N * 64;

    char* w = (char*)d_ws;
    auto carve = [&](size_t bytes) {
        char* p = w;
        w += (bytes + 255) & ~(size_t)255;
        return p;
    };
    unsigned short* h0b  = (unsigned short*)carve((size_t)N * 64 * 2);
    float* s_src   = (float*)carve((size_t)N * 4);
    float* s_dst   = (float*)carve((size_t)N * 4);
    float* inv_hs  = (float*)carve((size_t)N * 4);
    unsigned short* h_bf = (unsigned short*)carve((size_t)E * 2);
    int*   Hist    = (int*)  carve((size_t)NEB * NB * 4);
    int*   Base    = (int*)  carve((size_t)NEB * NB * 4);
    int*   coltot  = (int*)  carve((size_t)NB * 4);
    int*   boff    = (int*)  carve((size_t)NB * 4);
    int2*  binned  = (int2*) carve((size_t)E * 8);

    const int lgrid = (N + 255) / 256;         // 391 linear blocks (4 tiles/wave)

    k_linear_hist<<<lgrid + NEB, 256, 0, stream>>>(
        x, fc_w, a_w, a_b, h0b, s_src, s_dst, src, Hist, N, E, NB, lgrid);
    k_colscan<<<NB, 512, 0, stream>>>(Hist, Base, coltot, NEB, NB);
    k_bin<<<NEB, 512, 0, stream>>>(src, dst, adj, s_src, s_dst, coltot, Base,
                                   boff, binned, h_bf, E, NB, NEB);
    k_bucket<<<NB, 256, 0, stream>>>(binned, boff, coltot, h0b, out, inv_hs, N);
    k_alpha<<<(E / 4 + 255) / 256, 256, 0, stream>>>(src, h_bf, inv_hs, alpha, E);
}

// Round 24
// 108.994 us; speedup vs baseline: 1.1345x; 1.0054x over previous
//
#include <hip/hip_runtime.h>
#include <hip/hip_bf16.h>

// GAT layer, round 24: r23/r20 structure (109.6us, reproduced) with K1's
// MFMA linear software-pipelined: A-fragments double-buffered (load tile
// tt+1 while computing tile tt) -> 2x loads in flight, steady-state MFMA
// no longer waits on its own tile's loads. Everything else identical.
// N=100000, F=128, H=64, E=1.6M.

#define LEAKY 0.05f
#define BSH   6                  // nodes per bucket = 64
#define BSZ   64
#define EPB   4096               // edges per segment
#define MAXIT 6
#define CAPB  (MAXIT * 256)      // 1536 cap (mean 1023, +16 sigma)
#define NBMAX 2048               // NB = 1563
#define NXCD  8

using bf16x8 = __attribute__((ext_vector_type(8))) __bf16;
using f32x4  = __attribute__((ext_vector_type(4))) float;

__device__ __forceinline__ int wave_scan_incl(int v, int lane) {
#pragma unroll
    for (int off = 1; off < 64; off <<= 1) {
        int u = __shfl_up(v, off);
        if (lane >= off) v += u;
    }
    return v;
}
__device__ __forceinline__ unsigned short f2bf(float f) {   // RNE bf16
    unsigned u = __float_as_uint(f);
    return (unsigned short)((u + 0x7FFF + ((u >> 16) & 1)) >> 16);
}
__device__ __forceinline__ float bf2f(unsigned short u) {
    return __uint_as_float((unsigned)u << 16);
}
__device__ __forceinline__ bf16x8 pack8(const float* p) {
    float4 lo = *(const float4*)p;
    float4 hi = *(const float4*)(p + 4);
    bf16x8 v;
    v[0] = (__bf16)lo.x; v[1] = (__bf16)lo.y; v[2] = (__bf16)lo.z; v[3] = (__bf16)lo.w;
    v[4] = (__bf16)hi.x; v[5] = (__bf16)hi.y; v[6] = (__bf16)hi.z; v[7] = (__bf16)hi.w;
    return v;
}
__device__ __forceinline__ float leaky_exp(float t) {
    t = (t >= 0.f) ? t : LEAKY * t;
    return __expf(t);
}
// bijective XCD swizzle (m204): consecutive logical ids on same XCD
__device__ __forceinline__ int xcd_swz(int i, int n) {
    int q = n / NXCD, r = n % NXCD;
    int xcd = i % NXCD, j = i / NXCD;
    return (xcd < r) ? xcd * (q + 1) + j : r * (q + 1) + (xcd - r) * q + j;
}

// ---------------------------------------------------------------------------
// K1 (fused): blocks [0,lgrid) -> MFMA linear (4 tiles/wave, A dbuf);
// blocks [lgrid,..) -> histogram.
__global__ __launch_bounds__(256) void k_linear_hist(
    const float* __restrict__ x, const float* __restrict__ fc_w,
    const float* __restrict__ a_w, const float* __restrict__ a_b,
    unsigned short* __restrict__ h0b, float* __restrict__ s_src,
    float* __restrict__ s_dst,
    const int* __restrict__ src, int* __restrict__ Hist,
    int N, int E, int NB, int lgrid)
{
    __shared__ int hist[NBMAX];

    if (blockIdx.x >= lgrid) {
        const int seg = blockIdx.x - lgrid;
        for (int b = threadIdx.x; b < NB; b += 256) hist[b] = 0;
        __syncthreads();
        const int e0 = seg * EPB;
#pragma unroll
        for (int k = 0; k < EPB / 1024; ++k) {
            int e = e0 + k * 1024 + threadIdx.x * 4;
            if (e + 3 < E) {
                int4 s4 = *(const int4*)&src[e];
                atomicAdd(&hist[s4.x >> BSH], 1);
                atomicAdd(&hist[s4.y >> BSH], 1);
                atomicAdd(&hist[s4.z >> BSH], 1);
                atomicAdd(&hist[s4.w >> BSH], 1);
            } else {
                for (int q = e; q < E; ++q) atomicAdd(&hist[src[q] >> BSH], 1);
            }
        }
        __syncthreads();
        for (int b = threadIdx.x; b < NB; b += 256)
            Hist[seg * NB + b] = hist[b];
        return;
    }

    // ---- MFMA linear: one wave = 4 tiles = 64 nodes; A double-buffered ----
    const int wave = threadIdx.x >> 6, lane = threadIdx.x & 63;
    const int row = lane & 15, grp = lane >> 4;

    bf16x8 bf[4][4];
#pragma unroll
    for (int nt = 0; nt < 4; ++nt) {
        const float* wrow = fc_w + (size_t)(nt * 16 + row) * 128;
#pragma unroll
        for (int kb = 0; kb < 4; ++kb)
            bf[nt][kb] = pack8(wrow + kb * 32 + grp * 8);
    }
    float aw0[4], aw1[4];
#pragma unroll
    for (int nt = 0; nt < 4; ++nt) {
        aw0[nt] = a_w[nt * 16 + row];
        aw1[nt] = a_w[64 + nt * 16 + row];
    }
    const float ab = a_b[0];

    const int nbase = blockIdx.x * 256 + wave * 64;
    if (nbase >= N) return;

    // prefetch tile 0's A fragments
    bf16x8 afc[4], afn[4];
    {
        const int node0 = min(nbase + row, N - 1);
#pragma unroll
        for (int kb = 0; kb < 4; ++kb)
            afc[kb] = pack8(x + (size_t)node0 * 128 + kb * 32 + grp * 8);
    }

#pragma unroll
    for (int tt = 0; tt < 4; ++tt) {
        const int tbase = nbase + tt * 16;

        // issue next tile's A loads (overlaps with this tile's MFMAs)
        if (tt < 3) {
            const int nnode = min(tbase + 16 + row, N - 1);
#pragma unroll
            for (int kb = 0; kb < 4; ++kb)
                afn[kb] = pack8(x + (size_t)nnode * 128 + kb * 32 + grp * 8);
        }

        if (tbase < N) {
            f32x4 acc[4];
#pragma unroll
            for (int nt = 0; nt < 4; ++nt) acc[nt] = (f32x4){0.f, 0.f, 0.f, 0.f};

#pragma unroll
            for (int nt = 0; nt < 4; ++nt)
#pragma unroll
                for (int kb = 0; kb < 4; ++kb)
                    acc[nt] = __builtin_amdgcn_mfma_f32_16x16x32_bf16(
                        afc[kb], bf[nt][kb], acc[nt], 0, 0, 0);

#pragma unroll
            for (int nt = 0; nt < 4; ++nt)
#pragma unroll
                for (int r = 0; r < 4; ++r) {
                    int nrow = tbase + grp * 4 + r;
                    if (nrow < N)
                        h0b[(size_t)nrow * 64 + nt * 16 + row] = f2bf(acc[nt][r]);
                }

#pragma unroll
            for (int r = 0; r < 4; ++r) {
                float p0 = 0.f, p1 = 0.f;
#pragma unroll
                for (int nt = 0; nt < 4; ++nt) {
                    p0 += acc[nt][r] * aw0[nt];
                    p1 += acc[nt][r] * aw1[nt];
                }
#pragma unroll
                for (int off = 1; off < 16; off <<= 1) {
                    p0 += __shfl_xor(p0, off);
                    p1 += __shfl_xor(p1, off);
                }
                int nrow = tbase + grp * 4 + r;
                if (row == 0 && nrow < N) { s_src[nrow] = p0 + ab; s_dst[nrow] = p1; }
            }
        }

        // rotate buffers
#pragma unroll
        for (int kb = 0; kb < 4; ++kb) afc[kb] = afn[kb];
    }
}

// ---------------------------------------------------------------------------
// K2: column scan of Hist -> Base[seg][b] + coltot[b]   (NEB <= 512)
__global__ __launch_bounds__(512) void k_colscan(
    const int* __restrict__ Hist, int* __restrict__ Base,
    int* __restrict__ coltot, int NEB, int NB)
{
    __shared__ int wsum[8];
    const int b = blockIdx.x;
    const int t = threadIdx.x, wv = t >> 6, lane = t & 63;
    int v = (t < NEB) ? Hist[t * NB + b] : 0;
    int incl = wave_scan_incl(v, lane);
    if (lane == 63) wsum[wv] = incl;
    __syncthreads();
    int woff = 0;
    for (int w = 0; w < wv; ++w) woff += wsum[w];
    if (t < NEB) Base[t * NB + b] = woff + incl - v;
    if (t == NEB - 1) coltot[b] = woff + incl;
}

// ---------------------------------------------------------------------------
// K3: per-segment LDS sort + ORDERED global placement; streams h (bf16).
// Each block scans coltot -> local boff (ordered regions); block 0 publishes
// boff for k_bucket. blockIdx -> seg via bijective XCD swizzle.
__global__ __launch_bounds__(512) void k_bin(
    const int* __restrict__ src, const int* __restrict__ dst,
    const float* __restrict__ adj,
    const float* __restrict__ s_src, const float* __restrict__ s_dst,
    const int* __restrict__ coltot, const int* __restrict__ Base,
    int* __restrict__ boff,
    int2* __restrict__ binned, unsigned short* __restrict__ h_bf,
    int E, int NB, int NEB)
{
    __shared__ int  hist[NBMAX];     // counts -> local prefix -> cursor
    __shared__ int  gbase[NBMAX];    // lboff, then global base per bucket
    __shared__ int  wpart[8];
    __shared__ int2 stage[EPB];      // 32 KB
    __shared__ int  gaddr[EPB];      // 16 KB

    const int t = threadIdx.x;
    const int seg = xcd_swz(blockIdx.x, NEB);
    const int e0 = seg * EPB;
    const int segcnt = min(EPB, E - e0);
    const int lane = t & 63, wv = t >> 6;
    const int C = (NB + 511) / 512;  // 4 at NB=1563

    // ---- phase 0: scan coltot -> lboff (into gbase); block 0 -> boff ----
    {
        const int lo = t * C, hiB = min(NB, lo + C);
        int cv[4];
        int ssum = 0;
        for (int b = lo; b < hiB; ++b) { cv[b - lo] = coltot[b]; ssum += cv[b - lo]; }
        int incl = wave_scan_incl(ssum, lane);
        if (lane == 63) wpart[wv] = incl;
        __syncthreads();
        int woff = 0;
        for (int w2 = 0; w2 < wv; ++w2) woff += wpart[w2];
        int run = woff + incl - ssum;
        for (int b = lo; b < hiB; ++b) { gbase[b] = run; run += cv[b - lo]; }
        __syncthreads();
        if (blockIdx.x == 0)
            for (int b = t; b < NB; b += 512) boff[b] = gbase[b];
    }

    for (int b = t; b < NB; b += 512) hist[b] = 0;
    __syncthreads();

    // load 8 edges/thread, build records, LDS histogram, persist h_bf
    int rw0[8], rw1[8], bkt[8];
#pragma unroll
    for (int k = 0; k < 2; ++k) {
        int e = e0 + k * 2048 + t * 4;
        if (e + 3 < E) {
            int4   s4 = *(const int4*)&src[e];
            int4   d4 = *(const int4*)&dst[e];
            float4 a4 = *(const float4*)&adj[e];
            ushort4 hb;
#pragma unroll
            for (int q = 0; q < 4; ++q) {
                const int i = k * 4 + q;
                int s = (&s4.x)[q], d = (&d4.x)[q];
                float h = leaky_exp(s_src[s] + s_dst[d]);
                float v = h * (&a4.x)[q];
                unsigned short hb16 = f2bf(h);
                (&hb.x)[q] = hb16;
                rw0[i] = d | ((s & (BSZ - 1)) << 24);
                rw1[i] = (int)(((unsigned)hb16 << 16) | f2bf(v));
                bkt[i] = s >> BSH;
                atomicAdd(&hist[bkt[i]], 1);
            }
            *(ushort4*)&h_bf[e] = hb;
        } else {
#pragma unroll
            for (int q = 0; q < 4; ++q) {
                const int i = k * 4 + q;
                int ee = e + q;
                if (ee < E) {
                    int s = src[ee], d = dst[ee];
                    float h = leaky_exp(s_src[s] + s_dst[d]);
                    float v = h * adj[ee];
                    unsigned short hb16 = f2bf(h);
                    h_bf[ee] = hb16;
                    rw0[i] = d | ((s & (BSZ - 1)) << 24);
                    rw1[i] = (int)(((unsigned)hb16 << 16) | f2bf(v));
                    bkt[i] = s >> BSH;
                    atomicAdd(&hist[bkt[i]], 1);
                } else bkt[i] = -1;
            }
        }
    }
    __syncthreads();

    // block exclusive scan of hist[0..NB) in place (512 threads)
    {
        const int lo = t * C, hiB = min(NB, lo + C);
        int ssum = 0;
        for (int b = lo; b < hiB; ++b) ssum += hist[b];
        int incl = wave_scan_incl(ssum, lane);
        if (lane == 63) wpart[wv] = incl;
        __syncthreads();
        int woff = 0;
        for (int w2 = 0; w2 < wv; ++w2) woff += wpart[w2];
        int run = woff + incl - ssum;
        for (int b = lo; b < hiB; ++b) { int v = hist[b]; hist[b] = run; run += v; }
        __syncthreads();
    }

    // global base per bucket (hist keeps lpref and becomes the cursor)
    for (int b = t; b < NB; b += 512)
        gbase[b] = gbase[b] + Base[seg * NB + b] - hist[b];
    __syncthreads();

    // place records into sorted LDS slots + record their global address
#pragma unroll
    for (int i = 0; i < 8; ++i) {
        if (bkt[i] >= 0) {
            int pos = atomicAdd(&hist[bkt[i]], 1);
            stage[pos] = make_int2(rw0[i], rw1[i]);
            gaddr[pos] = gbase[bkt[i]] + pos;
        }
    }
    __syncthreads();

    // ordered write-out: consecutive j -> monotone ascending gaddr
    for (int j = t; j < segcnt; j += 512)
        binned[gaddr[j]] = stage[j];
}

// ---------------------------------------------------------------------------
// K4: per-bucket contiguous records -> LDS CSR + dual-node quad-gather.
// h packed in rec.y; h-sum folded into the shfl-reduce (no LDS float atomics).
__global__ __launch_bounds__(256) void k_bucket(
    const int2* __restrict__ binned, const int* __restrict__ boff,
    const int* __restrict__ coltot,
    const unsigned short* __restrict__ h0b, float* __restrict__ out,
    float* __restrict__ inv_hsum_g, int N)
{
    __shared__ int   deg_cur[BSZ];
    __shared__ int   pref[BSZ + 1];
    __shared__ int2  rec[CAPB];       // {dst, h_bf<<16 | v_bf}

    const int b   = blockIdx.x;
    const int lo  = boff[b];
    const int cnt = coltot[b];
    const int hi  = lo + cnt;
    const int n0 = b << BSH;
    const int nn = min(BSZ, N - n0);
    const int t = threadIdx.x, wv = t >> 6, lane = t & 63;

    if (t < BSZ) deg_cur[t] = 0;
    __syncthreads();

    if (cnt <= CAPB) {
        int2 r[MAXIT];
#pragma unroll
        for (int it = 0; it < MAXIT; ++it) {
            int j = lo + it * 256 + t;
            if (j < hi) r[it] = binned[j];
        }
#pragma unroll
        for (int it = 0; it < MAXIT; ++it)
            if (lo + it * 256 + t < hi)
                atomicAdd(&deg_cur[(unsigned)r[it].x >> 24], 1);
        __syncthreads();

        // single-wave scan over 64 degrees
        if (wv == 0) {
            int v = deg_cur[lane];
            int incl = wave_scan_incl(v, lane);
            pref[lane + 1] = incl;
            if (lane == 0) pref[0] = 0;
            deg_cur[lane] = incl - v;        // cursor = exclusive prefix
        }
        __syncthreads();

#pragma unroll
        for (int it = 0; it < MAXIT; ++it) {
            if (lo + it * 256 + t < hi) {
                int2 rr = r[it];
                int node = (unsigned)rr.x >> 24;
                int pos = atomicAdd(&deg_cur[node], 1);
                rec[pos] = make_int2(rr.x & 0xFFFFFF, rr.y);
            }
        }
        __syncthreads();

        // dual-node quad-gather: wave handles (nA, nA+4); h-sum in-reduce
        const int eslot = lane >> 4, fq = lane & 15;
        for (int nA = wv; nA < nn; nA += 8) {
            const int nB = nA + 4;
            const bool hasB = (nB < nn);
            const int sA = pref[nA], eA2 = pref[nA + 1];
            const int sB = hasB ? pref[nB] : 0, eB2 = hasB ? pref[nB + 1] : 0;

            float aA[4] = {0.f, 0.f, 0.f, 0.f}, bA[4] = {0.f, 0.f, 0.f, 0.f};
            float aB[4] = {0.f, 0.f, 0.f, 0.f}, bB[4] = {0.f, 0.f, 0.f, 0.f};
            float hA = 0.f, hB = 0.f;

            const int roundsA = (eA2 - sA + 7) >> 3;
            const int roundsB = (eB2 - sB + 7) >> 3;
            const int rounds  = max(roundsA, roundsB);

            for (int rr2 = 0; rr2 < rounds; ++rr2) {
                const int bA2 = sA + rr2 * 8;
                const int bB2 = sB + rr2 * 8;
                int idxA0 = bA2 + eslot,     idxA1 = bA2 + 4 + eslot;
                int idxB0 = bB2 + eslot,     idxB1 = bB2 + 4 + eslot;
                bool vA0 = idxA0 < eA2, vA1 = idxA1 < eA2;
                bool vB0 = hasB && idxB0 < eB2, vB1 = hasB && idxB1 < eB2;
                int2 rA0 = rec[vA0 ? idxA0 : 0];
                int2 rA1 = rec[vA1 ? idxA1 : 0];
                int2 rB0 = rec[vB0 ? idxB0 : 0];
                int2 rB1 = rec[vB1 ? idxB1 : 0];
                float valA0 = vA0 ? __uint_as_float((unsigned)rA0.y << 16) : 0.f;
                float valA1 = vA1 ? __uint_as_float((unsigned)rA1.y << 16) : 0.f;
                float valB0 = vB0 ? __uint_as_float((unsigned)rB0.y << 16) : 0.f;
                float valB1 = vB1 ? __uint_as_float((unsigned)rB1.y << 16) : 0.f;
                hA += (vA0 ? __uint_as_float((unsigned)rA0.y & 0xFFFF0000u) : 0.f)
                    + (vA1 ? __uint_as_float((unsigned)rA1.y & 0xFFFF0000u) : 0.f);
                hB += (vB0 ? __uint_as_float((unsigned)rB0.y & 0xFFFF0000u) : 0.f)
                    + (vB1 ? __uint_as_float((unsigned)rB1.y & 0xFFFF0000u) : 0.f);
                uint2 uA0 = *(const uint2*)(h0b + (size_t)rA0.x * 64 + fq * 4);
                uint2 uA1 = *(const uint2*)(h0b + (size_t)rA1.x * 64 + fq * 4);
                uint2 uB0 = *(const uint2*)(h0b + (size_t)rB0.x * 64 + fq * 4);
                uint2 uB1 = *(const uint2*)(h0b + (size_t)rB1.x * 64 + fq * 4);
                aA[0] += valA0 * __uint_as_float(uA0.x << 16);
                aA[1] += valA0 * __uint_as_float(uA0.x & 0xFFFF0000u);
                aA[2] += valA0 * __uint_as_float(uA0.y << 16);
                aA[3] += valA0 * __uint_as_float(uA0.y & 0xFFFF0000u);
                bA[0] += valA1 * __uint_as_float(uA1.x << 16);
                bA[1] += valA1 * __uint_as_float(uA1.x & 0xFFFF0000u);
                bA[2] += valA1 * __uint_as_float(uA1.y << 16);
                bA[3] += valA1 * __uint_as_float(uA1.y & 0xFFFF0000u);
                aB[0] += valB0 * __uint_as_float(uB0.x << 16);
                aB[1] += valB0 * __uint_as_float(uB0.x & 0xFFFF0000u);
                aB[2] += valB0 * __uint_as_float(uB0.y << 16);
                aB[3] += valB0 * __uint_as_float(uB0.y & 0xFFFF0000u);
                bB[0] += valB1 * __uint_as_float(uB1.x << 16);
                bB[1] += valB1 * __uint_as_float(uB1.x & 0xFFFF0000u);
                bB[2] += valB1 * __uint_as_float(uB1.y << 16);
                bB[3] += valB1 * __uint_as_float(uB1.y & 0xFFFF0000u);
            }

#pragma unroll
            for (int k = 0; k < 4; ++k) {
                float vv = aA[k] + bA[k];
                vv += __shfl_xor(vv, 16);
                vv += __shfl_xor(vv, 32);
                aA[k] = vv;
                float ww = aB[k] + bB[k];
                ww += __shfl_xor(ww, 16);
                ww += __shfl_xor(ww, 32);
                aB[k] = ww;
            }
            hA += __shfl_xor(hA, 16);
            hA += __shfl_xor(hA, 32);
            hB += __shfl_xor(hB, 16);
            hB += __shfl_xor(hB, 32);

            const float invA = (eA2 > sA) ? 1.0f / hA : 0.f;
            const float invB = (hasB && eB2 > sB) ? 1.0f / hB : 0.f;
            if (lane < 16) {
                float4 o;
                o.x = aA[0] * invA; o.y = aA[1] * invA;
                o.z = aA[2] * invA; o.w = aA[3] * invA;
                *(float4*)&out[(size_t)(n0 + nA) * 64 + fq * 4] = o;
            } else if (hasB && lane < 32) {
                float4 o;
                o.x = aB[0] * invB; o.y = aB[1] * invB;
                o.z = aB[2] * invB; o.w = aB[3] * invB;
                *(float4*)&out[(size_t)(n0 + nB) * 64 + fq * 4] = o;
            }
            if (lane == 0) inv_hsum_g[n0 + nA] = invA;
            if (hasB && lane == 16) inv_hsum_g[n0 + nB] = invB;
        }
    } else {
        // correctness-only fallback (cnt > CAPB is ~16 sigma; never expected)
        for (int n = wv; n < nn; n += 4) {
            float acc = 0.f, hs = 0.f;
            for (int j = lo; j < hi; ++j) {
                int2 rr = binned[j];
                if (((unsigned)rr.x >> 24) == (unsigned)n) {
                    hs  += __uint_as_float((unsigned)rr.y & 0xFFFF0000u);
                    acc += __uint_as_float((unsigned)rr.y << 16) *
                           bf2f(h0b[(size_t)(rr.x & 0xFFFFFF) * 64 + lane]);
                }
            }
            float inv = (hs > 0.f) ? 1.0f / hs : 0.f;
            out[(size_t)(n0 + n) * 64 + lane] = acc * inv;
            if (lane == 0) inv_hsum_g[n0 + n] = inv;
        }
    }
}

// ---------------------------------------------------------------------------
// K5: alpha[e] = h_bf[e] * inv_hsum[src[e]]  (pure stream, x4)
__global__ __launch_bounds__(256) void k_alpha(
    const int* __restrict__ src, const unsigned short* __restrict__ h_bf,
    const float* __restrict__ inv_hsum_g, float* __restrict__ alpha, int E)
{
    int i = blockIdx.x * 256 + threadIdx.x;
    int e = i * 4;
    if (e + 3 < E) {
        ushort4 hb = *(const ushort4*)&h_bf[e];
        int4 s4 = *(const int4*)&src[e];
        float4 a;
        a.x = bf2f(hb.x) * inv_hsum_g[s4.x];
        a.y = bf2f(hb.y) * inv_hsum_g[s4.y];
        a.z = bf2f(hb.z) * inv_hsum_g[s4.z];
        a.w = bf2f(hb.w) * inv_hsum_g[s4.w];
        *(float4*)&alpha[e] = a;
    } else {
        for (; e < E; ++e)
            alpha[e] = bf2f(h_bf[e]) * inv_hsum_g[src[e]];
    }
}

// ---------------------------------------------------------------------------
extern "C" void kernel_launch(void* const* d_in, const int* in_sizes, int n_in,
                              void* d_out, int out_size, void* d_ws, size_t ws_size,
                              hipStream_t stream)
{
    const float* x    = (const float*)d_in[0];
    const int*   ei   = (const int*)d_in[1];
    const float* adj  = (const float*)d_in[2];
    const float* fc_w = (const float*)d_in[3];
    const float* a_w  = (const float*)d_in[4];
    const float* a_b  = (const float*)d_in[5];

    const int N = in_sizes[0] / 128;          // 100000
    const int E = in_sizes[2];                // 1600000
    const int* src = ei;
    const int* dst = ei + E;

    const int NB  = (N + BSZ - 1) >> BSH;     // 1563 buckets
    const int NEB = (E + EPB - 1) / EPB;      // 391 segments

    float* out   = (float*)d_out;
    float* alpha = out + (size_t)N * 64;

    char* w = (char*)d_ws;
    auto carve = [&](size_t bytes) {
        char* p = w;
        w += (bytes + 255) & ~(size_t)255;
        return p;
    };
    unsigned short* h0b  = (unsigned short*)carve((size_t)N * 64 * 2);
    float* s_src   = (float*)carve((size_t)N * 4);
    float* s_dst   = (float*)carve((size_t)N * 4);
    float* inv_hs  = (float*)carve((size_t)N * 4);
    unsigned short* h_bf = (unsigned short*)carve((size_t)E * 2);
    int*   Hist    = (int*)  carve((size_t)NEB * NB * 4);
    int*   Base    = (int*)  carve((size_t)NEB * NB * 4);
    int*   coltot  = (int*)  carve((size_t)NB * 4);
    int*   boff    = (int*)  carve((size_t)NB * 4);
    int2*  binned  = (int2*) carve((size_t)E * 8);

    const int lgrid = (N + 255) / 256;         // 391 linear blocks (4 tiles/wave)

    k_linear_hist<<<lgrid + NEB, 256, 0, stream>>>(
        x, fc_w, a_w, a_b, h0b, s_src, s_dst, src, Hist, N, E, NB, lgrid);
    k_colscan<<<NB, 512, 0, stream>>>(Hist, Base, coltot, NEB, NB);
    k_bin<<<NEB, 512, 0, stream>>>(src, dst, adj, s_src, s_dst, coltot, Base,
                                   boff, binned, h_bf, E, NB, NEB);
    k_bucket<<<NB, 256, 0, stream>>>(binned, boff, coltot, h0b, out, inv_hs, N);
    k_alpha<<<(E / 4 + 255) / 256, 256, 0, stream>>>(src, h_bf, inv_hs, alpha, E);
}